// Round 7
// baseline (255.490 us; speedup 1.0000x reference)
//
#include <hip/hip_runtime.h>
#include <hip/hip_bf16.h>
#include <math.h>

#define MUL 8
#define NCOL 144   // 16*(1+3+5)
#define TSIZE 8192
#define TMAXLEN 8.0f
#define STG 68     // stage row stride (floats): 64 data + 4 pad, breaks 256B bank aliasing

__device__ __forceinline__ float silu_f(float x) { return x / (1.0f + __expf(-x)); }

// ---------------- node MLP -> Ai[N][8] (standalone: used by fallback tier) ----------------
__global__ void node_mlp_kernel(const int* __restrict__ A,
                                const float* __restrict__ emb_table,
                                const float* __restrict__ w1,
                                const float* __restrict__ b1,
                                const float* __restrict__ w2,
                                const float* __restrict__ b2,
                                float* __restrict__ Ai, int N) {
    __shared__ float s_w1[16 * 64];
    __shared__ float s_w2[64 * MUL];
    __shared__ float s_b1[64];
    __shared__ float s_b2[MUL];
    __shared__ float s_emb[10 * 16];
    for (int i = threadIdx.x; i < 16 * 64; i += blockDim.x) s_w1[i] = w1[i];
    for (int i = threadIdx.x; i < 64 * MUL; i += blockDim.x) s_w2[i] = w2[i];
    for (int i = threadIdx.x; i < 64; i += blockDim.x) s_b1[i] = b1[i];
    for (int i = threadIdx.x; i < MUL; i += blockDim.x) s_b2[i] = b2[i];
    for (int i = threadIdx.x; i < 160; i += blockDim.x) s_emb[i] = emb_table[i];
    __syncthreads();

    int n = blockIdx.x * blockDim.x + threadIdx.x;
    if (n >= N) return;
    int a = A[n];

    float h[64];
    #pragma unroll
    for (int j = 0; j < 64; j++) h[j] = s_b1[j];
    #pragma unroll 1
    for (int k = 0; k < 16; k++) {
        float ek = s_emb[a * 16 + k];
        #pragma unroll
        for (int j = 0; j < 64; j++) h[j] += ek * s_w1[k * 64 + j];
    }
    #pragma unroll
    for (int j = 0; j < 64; j++) h[j] = silu_f(h[j]);

    #pragma unroll 1
    for (int u = 0; u < MUL; u++) {
        float acc = s_b2[u];
        #pragma unroll
        for (int k = 0; k < 64; k++) acc += h[k] * s_w2[k * MUL + u];
        Ai[n * MUL + u] = acc;
    }
}

// ---------------- gate table (standalone, reg-friendly): 32 blocks x 256 ----------------
__global__ void __launch_bounds__(256, 1) gate_table_kernel(
        const float* __restrict__ fw1, const float* __restrict__ fb1,
        const float* __restrict__ fw2, const float* __restrict__ fb2,
        const float* __restrict__ fw3, const float* __restrict__ fb3,
        float4* __restrict__ tab) {
    int i = blockIdx.x * blockDim.x + threadIdx.x;
    if (i >= TSIZE) return;
    float len = (float)i * (TMAXLEN / TSIZE);
    float r = len * (17.0f / 5.0f);
    float h[64];
    #pragma unroll
    for (int j = 0; j < 64; j++) h[j] = fb1[j];
    #pragma unroll 1
    for (int k = 0; k < 16; k++) {
        float dk = r - (float)(k + 1);
        float ek = __expf(-dk * dk) * (4.0f / 1.12f);
        #pragma unroll
        for (int j = 0; j < 64; j++) h[j] += ek * fw1[k * 64 + j];
    }
    #pragma unroll
    for (int j = 0; j < 64; j++) h[j] = silu_f(h[j]);
    float g0 = fb3[0], g1 = fb3[3], g2 = fb3[9];
    #pragma unroll 1
    for (int j = 0; j < 64; j++) {
        float a = fb2[j];
        #pragma unroll
        for (int k = 0; k < 64; k++) a += h[k] * fw2[k * 64 + j];
        a = silu_f(a);
        g0 += a * fw3[j * 15 + 0];
        g1 += a * fw3[j * 15 + 3];
        g2 += a * fw3[j * 15 + 9];
    }
    tab[i] = make_float4(g0 * 0.125f, g1 * 0.125f, g2 * 0.125f, 0.f);
}

// ---------------- setup: tpw transpose + At[10][8] (1 block) ----------------
__global__ void __launch_bounds__(256, 1) setup_kernel(
        const float* __restrict__ emb_table,
        const float* __restrict__ aw1, const float* __restrict__ ab1,
        const float* __restrict__ aw2, const float* __restrict__ ab2,
        const float* __restrict__ tpw,
        float* __restrict__ At, float* __restrict__ tpwT) {
    // ---- tpw transpose (proven layout) ----
    const int pl[3] = {0, 3, 9};
    for (int i = threadIdx.x; i < 3072; i += 256) {
        int l = i >> 10, r = i & 1023;
        int u = r >> 7, v = (r >> 4) & 7, w = r & 15;
        tpwT[(l << 10) + (u << 7) + (w << 3) + v] = tpw[pl[l] * 1024 + r];
    }
    // ---- At[10][8]: node MLP per atom type (bitwise-identical loop order) ----
    int t = threadIdx.x;
    if (t < 80) {
        int ty = t >> 3, u = t & 7;
        float h[64];
        #pragma unroll
        for (int j = 0; j < 64; j++) h[j] = ab1[j];
        #pragma unroll 1
        for (int k = 0; k < 16; k++) {
            float ek = emb_table[ty * 16 + k];
            #pragma unroll
            for (int j = 0; j < 64; j++) h[j] += ek * aw1[k * 64 + j];
        }
        #pragma unroll
        for (int j = 0; j < 64; j++) h[j] = silu_f(h[j]);
        float acc = ab2[u];
        #pragma unroll
        for (int k = 0; k < 64; k++) acc += h[k] * aw2[k * MUL + u];
        At[ty * 8 + u] = acc;
    }
}

// ---------------- lean edge pass: count + rank + anyShift flag ----------------
__global__ void __launch_bounds__(256) count_rank_kernel(
        const int* __restrict__ edst, const float* __restrict__ shifts,
        int* __restrict__ count, int* __restrict__ rank, int* __restrict__ flag, int E) {
    int e = blockIdx.x * 256 + threadIdx.x;
    bool nz = false;
    if (e < E) {
        int d = edst[e];
        float sh0 = shifts[e * 3 + 0], sh1 = shifts[e * 3 + 1], sh2 = shifts[e * 3 + 2];
        nz = (sh0 != 0.f) || (sh1 != 0.f) || (sh2 != 0.f);
        rank[e] = atomicAdd(&count[d], 1);
    }
    if (__ballot(nz)) {
        if ((threadIdx.x & 63) == 0) atomicOr(flag, 1);
    }
}

// ---------------- CSR build (mid-tier helpers, proven) ----------------
__global__ void count_kernel(const int* __restrict__ edst, int* __restrict__ count, int E) {
    int e = blockIdx.x * blockDim.x + threadIdx.x;
    if (e < E) atomicAdd(&count[edst[e]], 1);
}

// single-block scan (fallback for huge N)
__global__ void scan_kernel(const int* __restrict__ count, int* __restrict__ off, int N) {
    __shared__ int sums[1024];
    int L = N + 1;
    int chunk = (L + 1023) / 1024;
    int t = threadIdx.x;
    int lo = t * chunk;
    int hi = lo + chunk; if (hi > L) hi = L;
    int local = 0;
    for (int i = lo; i < hi; i++) local += (i < N) ? count[i] : 0;
    sums[t] = local;
    __syncthreads();
    for (int s = 1; s < 1024; s <<= 1) {
        int v = (t >= s) ? sums[t - s] : 0;
        __syncthreads();
        sums[t] += v;
        __syncthreads();
    }
    int run = (t == 0) ? 0 : sums[t - 1];
    for (int i = lo; i < hi; i++) {
        off[i] = run;
        run += (i < N) ? count[i] : 0;
    }
}

// hierarchical scan, phase 1: per-block sums (256 counters per block)
__global__ void __launch_bounds__(256) scan_part_kernel(
        const int* __restrict__ count, int* __restrict__ bsum, int N) {
    __shared__ int red[256];
    int t = threadIdx.x;
    int idx = blockIdx.x * 256 + t;
    red[t] = (idx < N) ? count[idx] : 0;
    __syncthreads();
    #pragma unroll
    for (int s = 128; s > 0; s >>= 1) {
        if (t < s) red[t] += red[t + s];
        __syncthreads();
    }
    if (t == 0) bsum[blockIdx.x] = red[0];
}

// hierarchical scan, phase 2: exclusive scan of <=1024 block sums; writes off[N] = total
__global__ void __launch_bounds__(1024) scan_top_kernel(
        const int* __restrict__ bsum, int* __restrict__ bpre,
        int* __restrict__ off, int N, int nblk) {
    __shared__ int s[1024];
    int t = threadIdx.x;
    int v = (t < nblk) ? bsum[t] : 0;
    s[t] = v;
    __syncthreads();
    for (int d = 1; d < 1024; d <<= 1) {
        int x = (t >= d) ? s[t - d] : 0;
        __syncthreads();
        s[t] += x;
        __syncthreads();
    }
    if (t < nblk) bpre[t] = s[t] - v;       // exclusive prefix of block sums
    if (t == 1023) off[N] = s[1023];        // total = E
}

// hierarchical scan, phase 3: block-local exclusive scan + block offset
__global__ void __launch_bounds__(256) scan_write_kernel(
        const int* __restrict__ count, const int* __restrict__ bpre,
        int* __restrict__ off, int N) {
    __shared__ int s[256];
    int t = threadIdx.x;
    int idx = blockIdx.x * 256 + t;
    int c = (idx < N) ? count[idx] : 0;
    s[t] = c;
    __syncthreads();
    for (int d = 1; d < 256; d <<= 1) {
        int x = (t >= d) ? s[t - d] : 0;
        __syncthreads();
        s[t] += x;
        __syncthreads();
    }
    if (idx < N) off[idx] = bpre[blockIdx.x] + s[t] - c;
}

__global__ void fill_kernel(const int* __restrict__ edst, const int* __restrict__ off,
                            int* __restrict__ cursor, int* __restrict__ list, int E) {
    int e = blockIdx.x * blockDim.x + threadIdx.x;
    if (e >= E) return;
    int d = edst[e];
    int p = atomicAdd(&cursor[d], 1);
    list[off[d] + p] = e;
}

// atomic-free CSR fill using precomputed rank. Stores src directly when no shifts.
__global__ void __launch_bounds__(256) permute_kernel(
        const int* __restrict__ edst, const int* __restrict__ esrc,
        const int* __restrict__ rank, const int* __restrict__ off,
        const int* __restrict__ flagp, int* __restrict__ list, int E) {
    int e = blockIdx.x * 256 + threadIdx.x;
    if (e >= E) return;
    int d = edst[e];
    int p = off[d] + rank[e];
    list[p] = (*flagp) ? e : esrc[e];
}

// ======== tier-1 conv: 4 nodes/wave; As/Ad from 10-type table At (L1); flag-gated shifts ==
__global__ void __launch_bounds__(256) conv_at_kernel(
        const float* __restrict__ pos, const int* __restrict__ batch,
        const int* __restrict__ esrc,
        const float* __restrict__ shifts, const float* __restrict__ cell,
        const int* __restrict__ A, const float* __restrict__ At,
        const float* __restrict__ tpwT, const float4* __restrict__ gtab,
        const int* __restrict__ flagp, const int* __restrict__ off,
        const int* __restrict__ list,
        float* __restrict__ out, int N) {
    __shared__ float s_stage[4][17 * STG];  // per-wave: rows q=0..16 x 64 cols (4 nodes x 16 slots)
    __shared__ float s_Z[4][288];           // per-wave: 4 nodes x 72 (u*9+i)
    __shared__ float s_M[4][388];           // per-wave: [l*128 + w*8 + u]
    __shared__ float s_Ad[4][32];           // per-wave: 4 nodes x 8

    const int tid = threadIdx.x, wv = tid >> 6, lane = tid & 63;
    const int k = lane >> 4, s = lane & 15;
    const int base = blockIdx.x * 16 + wv * 4;
    const int n = base + k;
    const bool nv = (n < N);

    const int FL = *flagp;   // wave-uniform

    int b0 = nv ? off[n] : 0;
    int b1 = nv ? off[n + 1] : 0;
    int deg = b1 - b0;

    if (s < 8) {
        int an = nv ? A[n] : 0;
        s_Ad[wv][k * 8 + s] = nv ? At[an * 8 + s] : 0.f;
    }

    float px = 0.f, py = 0.f, pz = 0.f;
    if (nv && deg > 0) { px = pos[n * 3 + 0]; py = pos[n * 3 + 1]; pz = pos[n * 3 + 2]; }

    // rounds = ceil(max deg over the wave's 4 nodes / 16)
    int md = deg;
    md = max(md, __shfl_xor(md, 16));
    md = max(md, __shfl_xor(md, 32));
    int nrnd = (md + 15) >> 4;

    float* st = s_stage[wv];

    // z-pairs: lane (k,s) owns pairs p = s + 16*j of node k (p = u*9 + i < 72)
    float z[5];
    const float4* ruP[5];
    const float4* riP[5];
    #pragma unroll
    for (int j = 0; j < 5; j++) {
        int p = s + 16 * j;
        int u = (p < 72) ? (p / 9) : 0;
        int i = (p < 72) ? (p - 9 * u) : 0;
        ruP[j] = (const float4*)(st + u * STG + k * 16);
        riP[j] = (const float4*)(st + (8 + i) * STG + k * 16);
        z[j] = 0.f;
    }

    #pragma unroll 1
    for (int rnd = 0; rnd < nrnd; rnd++) {
        int sl = (rnd << 4) + s;
        float As[8], gy[9];
        #pragma unroll
        for (int u = 0; u < 8; u++) As[u] = 0.f;
        #pragma unroll
        for (int i = 0; i < 9; i++) gy[i] = 0.f;
        if (sl < deg) {
            int v = list[b0 + sl];
            int src;
            float sv0 = 0.f, sv1 = 0.f, sv2 = 0.f;
            if (FL) {
                int e = v;
                src = esrc[e];
                float sh0 = shifts[e * 3 + 0], sh1 = shifts[e * 3 + 1], sh2 = shifts[e * 3 + 2];
                if (sh0 != 0.f || sh1 != 0.f || sh2 != 0.f) {
                    int g = batch[src];
                    const float* cg = cell + g * 9;
                    sv0 = sh0 * cg[0] + sh1 * cg[3] + sh2 * cg[6];
                    sv1 = sh0 * cg[1] + sh1 * cg[4] + sh2 * cg[7];
                    sv2 = sh0 * cg[2] + sh1 * cg[5] + sh2 * cg[8];
                }
            } else {
                src = v;   // permute stored esrc[e] directly
            }
            float vx = px - pos[src * 3 + 0] + sv0;   // dst = n
            float vy = py - pos[src * 3 + 1] + sv1;
            float vz = pz - pos[src * 3 + 2] + sv2;
            float len = sqrtf(vx * vx + vy * vy + vz * vz);
            float inv = 1.0f / fmaxf(len, 1e-8f);
            float nx = vx * inv, ny = vy * inv, nz = vz * inv;

            float tp = fminf(len * ((float)TSIZE / TMAXLEN), (float)(TSIZE - 1));
            int ti = (int)tp; if (ti > TSIZE - 2) ti = TSIZE - 2;
            float fr = tp - (float)ti;
            float4 ga = gtab[ti], gb = gtab[ti + 1];
            float g0 = ga.x + fr * (gb.x - ga.x);
            float g1 = ga.y + fr * (gb.y - ga.y);
            float g2 = ga.z + fr * (gb.z - ga.z);

            const float s3c = 1.7320508075688772f;
            const float s15 = 3.872983346207417f;
            const float s5h = 1.118033988749895f;
            gy[0] = g0;
            gy[1] = g1 * (s3c * nx); gy[2] = g1 * (s3c * ny); gy[3] = g1 * (s3c * nz);
            gy[4] = g2 * (s15 * nx * ny); gy[5] = g2 * (s15 * ny * nz);
            gy[6] = g2 * (s5h * (3.f * nz * nz - 1.f));
            gy[7] = g2 * (s15 * nx * nz); gy[8] = g2 * (0.5f * s15 * (nx * nx - ny * ny));

            int a = A[src];
            const float4* Ap = (const float4*)(At + a * 8);   // 320B table, L1-resident
            float4 A0 = Ap[0], A1 = Ap[1];
            As[0] = A0.x; As[1] = A0.y; As[2] = A0.z; As[3] = A0.w;
            As[4] = A1.x; As[5] = A1.y; As[6] = A1.z; As[7] = A1.w;
        }
        // stage transposed: row q, column = lane (conflict-free writes)
        #pragma unroll
        for (int u = 0; u < 8; u++) st[u * STG + lane] = As[u];
        #pragma unroll
        for (int i = 0; i < 9; i++) st[(8 + i) * STG + lane] = gy[i];
        __builtin_amdgcn_wave_barrier();
        #pragma unroll
        for (int j = 0; j < 5; j++) {
            if (j < 4 || s < 8) {
                #pragma unroll
                for (int c = 0; c < 4; c++) {
                    float4 a = ruP[j][c], b = riP[j][c];
                    z[j] += a.x * b.x + a.y * b.y + a.z * b.z + a.w * b.w;
                }
            }
        }
        __builtin_amdgcn_wave_barrier();
    }

    // publish Z: node k, element p = u*9+i
    #pragma unroll
    for (int j = 0; j < 5; j++)
        if (j < 4 || s < 8) s_Z[wv][k * 72 + s + 16 * j] = z[j];
    __builtin_amdgcn_wave_barrier();

    // k-invariant decode for M phase (6 elems/lane) and out phase (3 cols/lane)
    const float4* twp[6];
    int moff[6];
    #pragma unroll
    for (int t = 0; t < 6; t++) {
        int m = lane + (t << 6);
        int l = m >> 7, r = m & 127, u = r >> 4, w = r & 15;
        twp[t] = (const float4*)(tpwT + (l << 10) + (u << 7) + (w << 3));
        moff[t] = (l << 7) + (w << 3) + u;
    }
    int moffo[3], zoff[3];
    bool ov[3];
    #pragma unroll
    for (int t = 0; t < 3; t++) {
        int c = lane + (t << 6);
        ov[t] = (c < NCOL);
        int cc = ov[t] ? c : 0;
        int l, w, ii;
        if (cc < 16)      { l = 0; w = cc;            ii = 0; }
        else if (cc < 64) { l = 1; w = (cc - 16) / 3; ii = 1 + (cc - 16) % 3; }
        else              { l = 2; w = (cc - 64) / 5; ii = 4 + (cc - 64) % 5; }
        moffo[t] = (l << 7) + (w << 3);
        zoff[t] = ii;
    }

    float* M = s_M[wv];
    float* Zb = s_Z[wv];
    #pragma unroll 1
    for (int k2 = 0; k2 < 4; k2++) {
        int nk = base + k2;
        float Adk[8];
        #pragma unroll
        for (int v = 0; v < 8; v++) Adk[v] = s_Ad[wv][k2 * 8 + v];  // broadcast
        #pragma unroll
        for (int t = 0; t < 6; t++) {
            float4 wa = twp[t][0], wb = twp[t][1];
            M[moff[t]] = Adk[0] * wa.x + Adk[1] * wa.y + Adk[2] * wa.z + Adk[3] * wa.w
                       + Adk[4] * wb.x + Adk[5] * wb.y + Adk[6] * wb.z + Adk[7] * wb.w;
        }
        int degk = __shfl(deg, k2 * 16);
        __builtin_amdgcn_wave_barrier();
        if (nk < N) {
            float dinv = 1.0f / fmaxf((float)degk, 1.0f);
            const float* Zk = Zb + k2 * 72;
            #pragma unroll
            for (int t = 0; t < 3; t++) {
                if (ov[t]) {
                    const float4* mm = (const float4*)(M + moffo[t]);
                    float4 m0 = mm[0], m1 = mm[1];
                    int ii = zoff[t];
                    float val = m0.x * Zk[0 + ii]  + m0.y * Zk[9 + ii]
                              + m0.z * Zk[18 + ii] + m0.w * Zk[27 + ii]
                              + m1.x * Zk[36 + ii] + m1.y * Zk[45 + ii]
                              + m1.z * Zk[54 + ii] + m1.w * Zk[63 + ii];
                    out[(size_t)nk * NCOL + lane + (t << 6)] = val * dinv;
                }
            }
        }
        __builtin_amdgcn_wave_barrier();
    }
}

// ======== mid-tier (proven round-5) prologue: gate table + tpw transpose + node MLP =========
__global__ void __launch_bounds__(256) prologue_kernel(
        const int* __restrict__ A, const float* __restrict__ emb_table,
        const float* __restrict__ aw1, const float* __restrict__ ab1,
        const float* __restrict__ aw2, const float* __restrict__ ab2,
        const float* __restrict__ fw1, const float* __restrict__ fb1,
        const float* __restrict__ fw2, const float* __restrict__ fb2,
        const float* __restrict__ fw3, const float* __restrict__ fb3,
        const float* __restrict__ tpw,
        float* __restrict__ Ai, float4* __restrict__ tab,
        float* __restrict__ tpwT, int N) {
    __shared__ float s_w1[16 * 64];
    __shared__ float s_w2[64 * MUL];
    __shared__ float s_b1[64];
    __shared__ float s_b2[MUL];
    __shared__ float s_emb[10 * 16];

    int b = blockIdx.x;
    if (b < 32) {
        int i = b * 256 + threadIdx.x;
        if (i >= TSIZE) return;
        float len = (float)i * (TMAXLEN / TSIZE);
        float r = len * (17.0f / 5.0f);
        float h[64];
        #pragma unroll
        for (int j = 0; j < 64; j++) h[j] = fb1[j];
        #pragma unroll 1
        for (int k = 0; k < 16; k++) {
            float dk = r - (float)(k + 1);
            float ek = __expf(-dk * dk) * (4.0f / 1.12f);
            #pragma unroll
            for (int j = 0; j < 64; j++) h[j] += ek * fw1[k * 64 + j];
        }
        #pragma unroll
        for (int j = 0; j < 64; j++) h[j] = silu_f(h[j]);
        float g0 = fb3[0], g1 = fb3[3], g2 = fb3[9];
        #pragma unroll 1
        for (int j = 0; j < 64; j++) {
            float a = fb2[j];
            #pragma unroll
            for (int k = 0; k < 64; k++) a += h[k] * fw2[k * 64 + j];
            a = silu_f(a);
            g0 += a * fw3[j * 15 + 0];
            g1 += a * fw3[j * 15 + 3];
            g2 += a * fw3[j * 15 + 9];
        }
        tab[i] = make_float4(g0 * 0.125f, g1 * 0.125f, g2 * 0.125f, 0.f);
    } else if (b == 32) {
        const int pl[3] = {0, 3, 9};
        for (int i = threadIdx.x; i < 3072; i += 256) {
            int l = i >> 10, r = i & 1023;
            int u = r >> 7, v = (r >> 4) & 7, w = r & 15;
            tpwT[(l << 10) + (u << 7) + (w << 3) + v] = tpw[pl[l] * 1024 + r];
        }
    } else {
        for (int i = threadIdx.x; i < 16 * 64; i += 256) s_w1[i] = aw1[i];
        for (int i = threadIdx.x; i < 64 * MUL; i += 256) s_w2[i] = aw2[i];
        for (int i = threadIdx.x; i < 64; i += 256) s_b1[i] = ab1[i];
        for (int i = threadIdx.x; i < MUL; i += 256) s_b2[i] = ab2[i];
        for (int i = threadIdx.x; i < 160; i += 256) s_emb[i] = emb_table[i];
        __syncthreads();

        int n = (b - 33) * 256 + threadIdx.x;
        if (n >= N) return;
        int a = A[n];

        float h[64];
        #pragma unroll
        for (int j = 0; j < 64; j++) h[j] = s_b1[j];
        #pragma unroll 1
        for (int k = 0; k < 16; k++) {
            float ek = s_emb[a * 16 + k];
            #pragma unroll
            for (int j = 0; j < 64; j++) h[j] += ek * s_w1[k * 64 + j];
        }
        #pragma unroll
        for (int j = 0; j < 64; j++) h[j] = silu_f(h[j]);

        #pragma unroll 1
        for (int u = 0; u < MUL; u++) {
            float acc = s_b2[u];
            #pragma unroll
            for (int k = 0; k < 64; k++) acc += h[k] * s_w2[k * MUL + u];
            Ai[n * MUL + u] = acc;
        }
    }
}

// ---- mid-tier conv (proven round-5): 4 nodes/wave, Ai-based ----
__global__ void __launch_bounds__(256) conv_node4_kernel(
        const float* __restrict__ pos, const int* __restrict__ batch,
        const int* __restrict__ esrc,
        const float* __restrict__ shifts, const float* __restrict__ cell,
        const float* __restrict__ tpwT, const float4* __restrict__ gtab,
        const float* __restrict__ Ai, const int* __restrict__ off,
        const int* __restrict__ list,
        float* __restrict__ out, int N) {
    __shared__ float s_stage[4][17 * STG];
    __shared__ float s_Z[4][288];
    __shared__ float s_M[4][388];
    __shared__ float s_Ad[4][32];

    const int tid = threadIdx.x, wv = tid >> 6, lane = tid & 63;
    const int k = lane >> 4, s = lane & 15;
    const int base = blockIdx.x * 16 + wv * 4;
    const int n = base + k;
    const bool nv = (n < N);

    int b0 = nv ? off[n] : 0;
    int b1 = nv ? off[n + 1] : 0;
    int deg = b1 - b0;

    if (s < 8) s_Ad[wv][k * 8 + s] = nv ? Ai[(size_t)n * MUL + s] : 0.f;

    float px = 0.f, py = 0.f, pz = 0.f;
    if (nv && deg > 0) { px = pos[n * 3 + 0]; py = pos[n * 3 + 1]; pz = pos[n * 3 + 2]; }

    int md = deg;
    md = max(md, __shfl_xor(md, 16));
    md = max(md, __shfl_xor(md, 32));
    int nrnd = (md + 15) >> 4;

    float* st = s_stage[wv];

    float z[5];
    const float4* ruP[5];
    const float4* riP[5];
    #pragma unroll
    for (int j = 0; j < 5; j++) {
        int p = s + 16 * j;
        int u = (p < 72) ? (p / 9) : 0;
        int i = (p < 72) ? (p - 9 * u) : 0;
        ruP[j] = (const float4*)(st + u * STG + k * 16);
        riP[j] = (const float4*)(st + (8 + i) * STG + k * 16);
        z[j] = 0.f;
    }

    #pragma unroll 1
    for (int rnd = 0; rnd < nrnd; rnd++) {
        int sl = (rnd << 4) + s;
        float As[8], gy[9];
        #pragma unroll
        for (int u = 0; u < 8; u++) As[u] = 0.f;
        #pragma unroll
        for (int i = 0; i < 9; i++) gy[i] = 0.f;
        if (sl < deg) {
            int e = list[b0 + sl];
            float sh0 = shifts[e * 3 + 0], sh1 = shifts[e * 3 + 1], sh2 = shifts[e * 3 + 2];
            int src = esrc[e];
            float sv0 = 0.f, sv1 = 0.f, sv2 = 0.f;
            if (sh0 != 0.f || sh1 != 0.f || sh2 != 0.f) {
                int g = batch[src];
                const float* cg = cell + g * 9;
                sv0 = sh0 * cg[0] + sh1 * cg[3] + sh2 * cg[6];
                sv1 = sh0 * cg[1] + sh1 * cg[4] + sh2 * cg[7];
                sv2 = sh0 * cg[2] + sh1 * cg[5] + sh2 * cg[8];
            }
            float vx = px - pos[src * 3 + 0] + sv0;
            float vy = py - pos[src * 3 + 1] + sv1;
            float vz = pz - pos[src * 3 + 2] + sv2;
            float len = sqrtf(vx * vx + vy * vy + vz * vz);
            float inv = 1.0f / fmaxf(len, 1e-8f);
            float nx = vx * inv, ny = vy * inv, nz = vz * inv;

            float tp = fminf(len * ((float)TSIZE / TMAXLEN), (float)(TSIZE - 1));
            int ti = (int)tp; if (ti > TSIZE - 2) ti = TSIZE - 2;
            float fr = tp - (float)ti;
            float4 ga = gtab[ti], gb = gtab[ti + 1];
            float g0 = ga.x + fr * (gb.x - ga.x);
            float g1 = ga.y + fr * (gb.y - ga.y);
            float g2 = ga.z + fr * (gb.z - ga.z);

            const float s3c = 1.7320508075688772f;
            const float s15 = 3.872983346207417f;
            const float s5h = 1.118033988749895f;
            gy[0] = g0;
            gy[1] = g1 * (s3c * nx); gy[2] = g1 * (s3c * ny); gy[3] = g1 * (s3c * nz);
            gy[4] = g2 * (s15 * nx * ny); gy[5] = g2 * (s15 * ny * nz);
            gy[6] = g2 * (s5h * (3.f * nz * nz - 1.f));
            gy[7] = g2 * (s15 * nx * nz); gy[8] = g2 * (0.5f * s15 * (nx * nx - ny * ny));

            const float4* Ap = (const float4*)(Ai + (size_t)src * MUL);
            float4 A0 = Ap[0], A1 = Ap[1];
            As[0] = A0.x; As[1] = A0.y; As[2] = A0.z; As[3] = A0.w;
            As[4] = A1.x; As[5] = A1.y; As[6] = A1.z; As[7] = A1.w;
        }
        #pragma unroll
        for (int u = 0; u < 8; u++) st[u * STG + lane] = As[u];
        #pragma unroll
        for (int i = 0; i < 9; i++) st[(8 + i) * STG + lane] = gy[i];
        __builtin_amdgcn_wave_barrier();
        #pragma unroll
        for (int j = 0; j < 5; j++) {
            if (j < 4 || s < 8) {
                #pragma unroll
                for (int c = 0; c < 4; c++) {
                    float4 a = ruP[j][c], b = riP[j][c];
                    z[j] += a.x * b.x + a.y * b.y + a.z * b.z + a.w * b.w;
                }
            }
        }
        __builtin_amdgcn_wave_barrier();
    }

    #pragma unroll
    for (int j = 0; j < 5; j++)
        if (j < 4 || s < 8) s_Z[wv][k * 72 + s + 16 * j] = z[j];
    __builtin_amdgcn_wave_barrier();

    const float4* twp[6];
    int moff[6];
    #pragma unroll
    for (int t = 0; t < 6; t++) {
        int m = lane + (t << 6);
        int l = m >> 7, r = m & 127, u = r >> 4, w = r & 15;
        twp[t] = (const float4*)(tpwT + (l << 10) + (u << 7) + (w << 3));
        moff[t] = (l << 7) + (w << 3) + u;
    }
    int moffo[3], zoff[3];
    bool ov[3];
    #pragma unroll
    for (int t = 0; t < 3; t++) {
        int c = lane + (t << 6);
        ov[t] = (c < NCOL);
        int cc = ov[t] ? c : 0;
        int l, w, ii;
        if (cc < 16)      { l = 0; w = cc;            ii = 0; }
        else if (cc < 64) { l = 1; w = (cc - 16) / 3; ii = 1 + (cc - 16) % 3; }
        else              { l = 2; w = (cc - 64) / 5; ii = 4 + (cc - 64) % 5; }
        moffo[t] = (l << 7) + (w << 3);
        zoff[t] = ii;
    }

    float* M = s_M[wv];
    float* Zb = s_Z[wv];
    #pragma unroll 1
    for (int k2 = 0; k2 < 4; k2++) {
        int nk = base + k2;
        float Adk[8];
        #pragma unroll
        for (int v = 0; v < 8; v++) Adk[v] = s_Ad[wv][k2 * 8 + v];
        #pragma unroll
        for (int t = 0; t < 6; t++) {
            float4 wa = twp[t][0], wb = twp[t][1];
            M[moff[t]] = Adk[0] * wa.x + Adk[1] * wa.y + Adk[2] * wa.z + Adk[3] * wa.w
                       + Adk[4] * wb.x + Adk[5] * wb.y + Adk[6] * wb.z + Adk[7] * wb.w;
        }
        int degk = __shfl(deg, k2 * 16);
        __builtin_amdgcn_wave_barrier();
        if (nk < N) {
            float dinv = 1.0f / fmaxf((float)degk, 1.0f);
            const float* Zk = Zb + k2 * 72;
            #pragma unroll
            for (int t = 0; t < 3; t++) {
                if (ov[t]) {
                    const float4* mm = (const float4*)(M + moffo[t]);
                    float4 m0 = mm[0], m1 = mm[1];
                    int ii = zoff[t];
                    float val = m0.x * Zk[0 + ii]  + m0.y * Zk[9 + ii]
                              + m0.z * Zk[18 + ii] + m0.w * Zk[27 + ii]
                              + m1.x * Zk[36 + ii] + m1.y * Zk[45 + ii]
                              + m1.z * Zk[54 + ii] + m1.w * Zk[63 + ii];
                    out[(size_t)nk * NCOL + lane + (t << 6)] = val * dinv;
                }
            }
        }
        __builtin_amdgcn_wave_barrier();
    }
}

// ================= fallback (small ws): atomic path =================
__global__ void __launch_bounds__(256) edge_atomic_kernel(
        const float* __restrict__ pos, const int* __restrict__ batch,
        const int* __restrict__ esrc, const int* __restrict__ edst,
        const float* __restrict__ shifts, const float* __restrict__ cell,
        const float* __restrict__ fw1, const float* __restrict__ fb1,
        const float* __restrict__ fw2, const float* __restrict__ fb2,
        const float* __restrict__ fw3, const float* __restrict__ fb3,
        const float* __restrict__ tpw,
        const float* __restrict__ Ai,
        float* __restrict__ out, float* __restrict__ deg, int E) {
    __shared__ float s_w1[16 * 64];
    __shared__ float s_w2[64 * 64];
    __shared__ float s_w3[64 * 3];
    __shared__ float s_b1[64];
    __shared__ float s_b2[64];
    __shared__ float s_b3[3];
    __shared__ float s_tpw[3 * 1024];
    for (int i = threadIdx.x; i < 1024; i += blockDim.x) s_w1[i] = fw1[i];
    for (int i = threadIdx.x; i < 4096; i += blockDim.x) s_w2[i] = fw2[i];
    for (int i = threadIdx.x; i < 64; i += blockDim.x) { s_b1[i] = fb1[i]; s_b2[i] = fb2[i]; }
    for (int i = threadIdx.x; i < 192; i += blockDim.x) {
        int j = i / 3, c = i - 3 * j;
        int cc = (c == 0) ? 0 : ((c == 1) ? 3 : 9);
        s_w3[i] = fw3[j * 15 + cc];
    }
    if (threadIdx.x < 3) {
        int cc = (threadIdx.x == 0) ? 0 : ((threadIdx.x == 1) ? 3 : 9);
        s_b3[threadIdx.x] = fb3[cc];
    }
    for (int i = threadIdx.x; i < 3 * 1024; i += blockDim.x) {
        int l = i >> 10, r = i & 1023;
        int p = (l == 0) ? 0 : ((l == 1) ? 3 : 9);
        s_tpw[i] = tpw[p * 1024 + r];
    }
    __syncthreads();
    int e = blockIdx.x * blockDim.x + threadIdx.x;
    if (e >= E) return;
    int s = esrc[e], d = edst[e];
    int g = batch[s];
    float sh0 = shifts[e * 3 + 0], sh1 = shifts[e * 3 + 1], sh2 = shifts[e * 3 + 2];
    const float* cg = cell + g * 9;
    float sv0 = sh0 * cg[0] + sh1 * cg[3] + sh2 * cg[6];
    float sv1 = sh0 * cg[1] + sh1 * cg[4] + sh2 * cg[7];
    float sv2 = sh0 * cg[2] + sh1 * cg[5] + sh2 * cg[8];
    float vx = pos[d * 3 + 0] - pos[s * 3 + 0] + sv0;
    float vy = pos[d * 3 + 1] - pos[s * 3 + 1] + sv1;
    float vz = pos[d * 3 + 2] - pos[s * 3 + 2] + sv2;
    float len = sqrtf(vx * vx + vy * vy + vz * vz);
    float inv = 1.0f / fmaxf(len, 1e-8f);
    float nx = vx * inv, ny = vy * inv, nz = vz * inv;
    float r = len * (17.0f / 5.0f);
    float h[64];
    #pragma unroll
    for (int j = 0; j < 64; j++) h[j] = s_b1[j];
    #pragma unroll 1
    for (int k = 0; k < 16; k++) {
        float dk = r - (float)(k + 1);
        float ek = __expf(-dk * dk) * (4.0f / 1.12f);
        #pragma unroll
        for (int j = 0; j < 64; j++) h[j] += ek * s_w1[k * 64 + j];
    }
    #pragma unroll
    for (int j = 0; j < 64; j++) h[j] = silu_f(h[j]);
    float g0 = s_b3[0], g1 = s_b3[1], g2 = s_b3[2];
    #pragma unroll 2
    for (int j = 0; j < 64; j++) {
        float a = s_b2[j];
        #pragma unroll
        for (int k = 0; k < 64; k++) a += h[k] * s_w2[k * 64 + j];
        a = silu_f(a);
        g0 += a * s_w3[j * 3 + 0];
        g1 += a * s_w3[j * 3 + 1];
        g2 += a * s_w3[j * 3 + 2];
    }
    g0 *= 0.125f; g1 *= 0.125f; g2 *= 0.125f;
    float t0[16], t1[16], t2[16];
    #pragma unroll
    for (int w = 0; w < 16; w++) { t0[w] = 0.f; t1[w] = 0.f; t2[w] = 0.f; }
    int s8 = s * MUL, d8 = d * MUL;
    float Ad[8];
    #pragma unroll
    for (int v = 0; v < 8; v++) Ad[v] = Ai[d8 + v];
    #pragma unroll 1
    for (int u = 0; u < 8; u++) {
        float asu = Ai[s8 + u];
        int offp = u * 128;
        #pragma unroll
        for (int v = 0; v < 8; v++) {
            float p = asu * Ad[v];
            int o2 = offp + v * 16;
            #pragma unroll
            for (int w = 0; w < 16; w++) {
                t0[w] += p * s_tpw[o2 + w];
                t1[w] += p * s_tpw[1024 + o2 + w];
                t2[w] += p * s_tpw[2048 + o2 + w];
            }
        }
    }
    #pragma unroll
    for (int w = 0; w < 16; w++) { t0[w] *= g0; t1[w] *= g1; t2[w] *= g2; }
    const float s3 = 1.7320508075688772f;
    const float s15 = 3.872983346207417f;
    const float s5h = 1.118033988749895f;
    float y1_[3] = { s3 * nx, s3 * ny, s3 * nz };
    float y2_[5] = { s15 * nx * ny, s15 * ny * nz, s5h * (3.f * nz * nz - 1.f),
                     s15 * nx * nz, 0.5f * s15 * (nx * nx - ny * ny) };
    float* o = out + (size_t)d * NCOL;
    #pragma unroll
    for (int w = 0; w < 16; w++) atomicAdd(o + w, t0[w]);
    #pragma unroll
    for (int w = 0; w < 16; w++)
        #pragma unroll
        for (int i = 0; i < 3; i++) atomicAdd(o + 16 + w * 3 + i, t1[w] * y1_[i]);
    #pragma unroll
    for (int w = 0; w < 16; w++)
        #pragma unroll
        for (int i = 0; i < 5; i++) atomicAdd(o + 64 + w * 5 + i, t2[w] * y2_[i]);
    atomicAdd(deg + d, 1.0f);
}

__global__ void finalize_kernel(float* __restrict__ out, const float* __restrict__ deg, int total) {
    int idx = blockIdx.x * blockDim.x + threadIdx.x;
    if (idx >= total) return;
    int n = idx / NCOL;
    out[idx] = out[idx] / fmaxf(deg[n], 1.0f);
}

extern "C" void kernel_launch(void* const* d_in, const int* in_sizes, int n_in,
                              void* d_out, int out_size, void* d_ws, size_t ws_size,
                              hipStream_t stream) {
    const float* pos    = (const float*)d_in[0];
    const int*   A      = (const int*)d_in[1];
    const int*   batch  = (const int*)d_in[2];
    const int*   esrc   = (const int*)d_in[3];
    const int*   edst   = (const int*)d_in[4];
    const float* shifts = (const float*)d_in[5];
    const float* cellp  = (const float*)d_in[6];
    const float* embt   = (const float*)d_in[7];
    const float* aw1    = (const float*)d_in[8];
    const float* ab1    = (const float*)d_in[9];
    const float* aw2    = (const float*)d_in[10];
    const float* ab2    = (const float*)d_in[11];
    const float* fw1    = (const float*)d_in[12];
    const float* fb1    = (const float*)d_in[13];
    const float* fw2    = (const float*)d_in[14];
    const float* fb2    = (const float*)d_in[15];
    const float* fw3    = (const float*)d_in[16];
    const float* fb3    = (const float*)d_in[17];
    const float* tpw    = (const float*)d_in[18];

    int N = in_sizes[1];
    int E = in_sizes[3];
    float* out = (float*)d_out;

    int nblk = (N + 255) / 256;
    int eblk = (E + 255) / 256;

    // NEW tier: count[N] | flag[1] | off[N+1] | rank[E] | list[E] | gtab | tpwT | At[80] | bsum | bpre
    size_t need_new = ((size_t)N + 1 + (size_t)(N + 1) + (size_t)E * 2) * 4
                    + (size_t)TSIZE * 16 + 3072 * 4 + 320 + 8192 + 768;
    // mid tier (round-5 proven): Ai | count | cursor | off | list | gtab | tpwT | bsum | bpre
    size_t need_mid = (size_t)N * 32 + (size_t)N * 8 + (size_t)(N + 1) * 4
                    + (size_t)E * 4 + (size_t)TSIZE * 16 + 3072 * 4 + 8192 + 1024;

    if (ws_size >= need_new && nblk <= 1024) {
        int*    count = (int*)d_ws;
        int*    flag  = count + N;
        int*    off   = flag + 1;
        int*    rank  = off + (N + 1);
        int*    list  = rank + E;
        float4* gtab  = (float4*)(((uintptr_t)(list + E) + 255) & ~(uintptr_t)255);
        float*  tpwT  = (float*)(gtab + TSIZE);
        float*  At    = tpwT + 3072;
        int*    bsum  = (int*)(At + 80);
        int*    bpre  = bsum + 1024;

        hipMemsetAsync(count, 0, ((size_t)N + 1) * sizeof(int), stream);  // count + flag

        gate_table_kernel<<<TSIZE / 256, 256, 0, stream>>>(fw1, fb1, fw2, fb2, fw3, fb3, gtab);
        setup_kernel<<<1, 256, 0, stream>>>(embt, aw1, ab1, aw2, ab2, tpw, At, tpwT);
        count_rank_kernel<<<eblk, 256, 0, stream>>>(edst, shifts, count, rank, flag, E);

        scan_part_kernel<<<nblk, 256, 0, stream>>>(count, bsum, N);
        scan_top_kernel<<<1, 1024, 0, stream>>>(bsum, bpre, off, N, nblk);
        scan_write_kernel<<<nblk, 256, 0, stream>>>(count, bpre, off, N);

        permute_kernel<<<eblk, 256, 0, stream>>>(edst, esrc, rank, off, flag, list, E);

        conv_at_kernel<<<(N + 15) / 16, 256, 0, stream>>>(
            pos, batch, esrc, shifts, cellp, A, At, tpwT, gtab, flag, off, list, out, N);
    } else if (ws_size >= need_mid) {
        float*  Ai     = (float*)d_ws;
        int*    count  = (int*)(Ai + (size_t)N * MUL);
        int*    cursor = count + N;
        int*    off    = cursor + N;
        int*    list   = off + (N + 1);
        float4* gtab   = (float4*)(((uintptr_t)(list + E) + 255) & ~(uintptr_t)255);
        float*  tpwT   = (float*)(gtab + TSIZE);
        int*    bsum   = (int*)(tpwT + 3072);
        int*    bpre   = bsum + 1024;

        hipMemsetAsync(count, 0, (size_t)N * 2 * sizeof(int), stream);  // count + cursor

        prologue_kernel<<<33 + nblk, 256, 0, stream>>>(
            A, embt, aw1, ab1, aw2, ab2, fw1, fb1, fw2, fb2, fw3, fb3,
            tpw, Ai, gtab, tpwT, N);
        count_kernel<<<eblk, 256, 0, stream>>>(edst, count, E);

        if (nblk <= 1024) {
            scan_part_kernel<<<nblk, 256, 0, stream>>>(count, bsum, N);
            scan_top_kernel<<<1, 1024, 0, stream>>>(bsum, bpre, off, N, nblk);
            scan_write_kernel<<<nblk, 256, 0, stream>>>(count, bpre, off, N);
        } else {
            scan_kernel<<<1, 1024, 0, stream>>>(count, off, N);
        }

        fill_kernel<<<eblk, 256, 0, stream>>>(edst, off, cursor, list, E);

        conv_node4_kernel<<<(N + 15) / 16, 256, 0, stream>>>(
            pos, batch, esrc, shifts, cellp, tpwT, gtab, Ai, off, list, out, N);
    } else {
        float* Ai  = (float*)d_ws;
        float* deg = Ai + (size_t)N * MUL;
        hipMemsetAsync(out, 0, (size_t)out_size * sizeof(float), stream);
        hipMemsetAsync(deg, 0, (size_t)N * sizeof(float), stream);
        node_mlp_kernel<<<(N + 255) / 256, 256, 0, stream>>>(A, embt, aw1, ab1, aw2, ab2, Ai, N);
        edge_atomic_kernel<<<eblk, 256, 0, stream>>>(
            pos, batch, esrc, edst, shifts, cellp,
            fw1, fb1, fw2, fb2, fw3, fb3, tpw, Ai, out, deg, E);
        int total = N * NCOL;
        finalize_kernel<<<(total + 255) / 256, 256, 0, stream>>>(out, deg, total);
    }
}

// Round 8
// 199.942 us; speedup vs baseline: 1.2778x; 1.2778x over previous
//
#include <hip/hip_runtime.h>
#include <hip/hip_bf16.h>
#include <math.h>

#define MUL 8
#define NCOL 144   // 16*(1+3+5)
#define TSIZE 8192
#define TMAXLEN 8.0f
#define STG 68     // stage row stride (floats): 64 data + 4 pad, breaks 256B bank aliasing
#define GBLK 512   // gate-table blocks in front_kernel

__device__ __forceinline__ float silu_f(float x) { return x / (1.0f + __expf(-x)); }

// ---------------- node MLP -> Ai[N][8] (standalone: used by fallback tier) ----------------
__global__ void node_mlp_kernel(const int* __restrict__ A,
                                const float* __restrict__ emb_table,
                                const float* __restrict__ w1,
                                const float* __restrict__ b1,
                                const float* __restrict__ w2,
                                const float* __restrict__ b2,
                                float* __restrict__ Ai, int N) {
    __shared__ float s_w1[16 * 64];
    __shared__ float s_w2[64 * MUL];
    __shared__ float s_b1[64];
    __shared__ float s_b2[MUL];
    __shared__ float s_emb[10 * 16];
    for (int i = threadIdx.x; i < 16 * 64; i += blockDim.x) s_w1[i] = w1[i];
    for (int i = threadIdx.x; i < 64 * MUL; i += blockDim.x) s_w2[i] = w2[i];
    for (int i = threadIdx.x; i < 64; i += blockDim.x) s_b1[i] = b1[i];
    for (int i = threadIdx.x; i < MUL; i += blockDim.x) s_b2[i] = b2[i];
    for (int i = threadIdx.x; i < 160; i += blockDim.x) s_emb[i] = emb_table[i];
    __syncthreads();

    int n = blockIdx.x * blockDim.x + threadIdx.x;
    if (n >= N) return;
    int a = A[n];

    float h[64];
    #pragma unroll
    for (int j = 0; j < 64; j++) h[j] = s_b1[j];
    #pragma unroll 1
    for (int k = 0; k < 16; k++) {
        float ek = s_emb[a * 16 + k];
        #pragma unroll
        for (int j = 0; j < 64; j++) h[j] += ek * s_w1[k * 64 + j];
    }
    #pragma unroll
    for (int j = 0; j < 64; j++) h[j] = silu_f(h[j]);

    #pragma unroll 1
    for (int u = 0; u < MUL; u++) {
        float acc = s_b2[u];
        #pragma unroll
        for (int k = 0; k < 64; k++) acc += h[k] * s_w2[k * MUL + u];
        Ai[n * MUL + u] = acc;
    }
}

// ======== tier-1 front kernel: wave-cooperative gate table + transpose/At + edge pass ========
// blocks [0,GBLK):    gate table, one entry per wave per pass (lane j owns h[j], a[j])
// block  GBLK:        tpw transpose + At[10][8] (wave-cooperative MLP, one type per wave)
// blocks (GBLK,...]:  edge pass: rank[e] = atomicAdd(count[edst[e]]), anyShift flag
__global__ void __launch_bounds__(256) front_kernel(
        const int* __restrict__ edst, const float* __restrict__ shifts,
        const float* __restrict__ emb_table,
        const float* __restrict__ aw1, const float* __restrict__ ab1,
        const float* __restrict__ aw2, const float* __restrict__ ab2,
        const float* __restrict__ fw1, const float* __restrict__ fb1,
        const float* __restrict__ fw2, const float* __restrict__ fb2,
        const float* __restrict__ fw3, const float* __restrict__ fb3,
        const float* __restrict__ tpw,
        int* __restrict__ count, int* __restrict__ rank, int* __restrict__ flag,
        float* __restrict__ At, float4* __restrict__ tab,
        float* __restrict__ tpwT, int E) {
    const int b = blockIdx.x;
    const int lane = threadIdx.x & 63, wv = threadIdx.x >> 6;

    if (b < GBLK) {
        // ---- gate table, wave-cooperative: lane j owns column j of the 64-wide MLP ----
        int gw = b * 4 + wv;
        #pragma unroll 1
        for (int e = gw; e < TSIZE; e += GBLK * 4) {
            float len = (float)e * (TMAXLEN / TSIZE);
            float r = len * (17.0f / 5.0f);
            // layer 1 (same k-ascending order as before)
            float h = fb1[lane];
            #pragma unroll
            for (int k = 0; k < 16; k++) {
                float dk = r - (float)(k + 1);
                float ek = __expf(-dk * dk) * (4.0f / 1.12f);
                h += ek * fw1[k * 64 + lane];
            }
            h = silu_f(h);
            // layer 2: a_j = fb2[j] + sum_k h[k]*fw2[k][j], k ascending via broadcast
            float a = fb2[lane];
            #pragma unroll
            for (int k = 0; k < 64; k++) a += __shfl(h, k) * fw2[k * 64 + lane];
            a = silu_f(a);
            // layer 3: per-lane product, tree-reduce over lanes
            float g0 = a * fw3[lane * 15 + 0];
            float g1 = a * fw3[lane * 15 + 3];
            float g2 = a * fw3[lane * 15 + 9];
            #pragma unroll
            for (int off = 32; off > 0; off >>= 1) {
                g0 += __shfl_xor(g0, off);
                g1 += __shfl_xor(g1, off);
                g2 += __shfl_xor(g2, off);
            }
            if (lane == 0)
                tab[e] = make_float4((fb3[0] + g0) * 0.125f,
                                     (fb3[3] + g1) * 0.125f,
                                     (fb3[9] + g2) * 0.125f, 0.f);
        }
    } else if (b == GBLK) {
        // ---- tpw transpose (proven layout) ----
        const int pl[3] = {0, 3, 9};
        for (int i = threadIdx.x; i < 3072; i += 256) {
            int l = i >> 10, r = i & 1023;
            int u = r >> 7, v = (r >> 4) & 7, w = r & 15;
            tpwT[(l << 10) + (u << 7) + (w << 3) + v] = tpw[pl[l] * 1024 + r];
        }
        // ---- At[10][8], wave-cooperative: one type per wave per pass ----
        #pragma unroll 1
        for (int ty = wv; ty < 10; ty += 4) {
            float h = ab1[lane];
            #pragma unroll
            for (int k = 0; k < 16; k++) h += emb_table[ty * 16 + k] * aw1[k * 64 + lane];
            h = silu_f(h);
            float p[8];
            #pragma unroll
            for (int u = 0; u < 8; u++) p[u] = h * aw2[lane * MUL + u];
            #pragma unroll
            for (int off = 32; off > 0; off >>= 1)
                #pragma unroll
                for (int u = 0; u < 8; u++) p[u] += __shfl_xor(p[u], off);
            if (lane == 0) {
                #pragma unroll
                for (int u = 0; u < 8; u++) At[ty * MUL + u] = ab2[u] + p[u];
            }
        }
    } else {
        // ---- edge pass: count + rank + anyShift flag ----
        int e = (b - GBLK - 1) * 256 + threadIdx.x;
        bool nz = false;
        if (e < E) {
            int d = edst[e];
            float sh0 = shifts[e * 3 + 0], sh1 = shifts[e * 3 + 1], sh2 = shifts[e * 3 + 2];
            nz = (sh0 != 0.f) || (sh1 != 0.f) || (sh2 != 0.f);
            rank[e] = atomicAdd(&count[d], 1);
        }
        if (__ballot(nz)) {
            if (lane == 0) atomicOr(flag, 1);
        }
    }
}

// ---------------- CSR build (mid-tier helpers, proven) ----------------
__global__ void count_kernel(const int* __restrict__ edst, int* __restrict__ count, int E) {
    int e = blockIdx.x * blockDim.x + threadIdx.x;
    if (e < E) atomicAdd(&count[edst[e]], 1);
}

// single-block scan (fallback for huge N)
__global__ void scan_kernel(const int* __restrict__ count, int* __restrict__ off, int N) {
    __shared__ int sums[1024];
    int L = N + 1;
    int chunk = (L + 1023) / 1024;
    int t = threadIdx.x;
    int lo = t * chunk;
    int hi = lo + chunk; if (hi > L) hi = L;
    int local = 0;
    for (int i = lo; i < hi; i++) local += (i < N) ? count[i] : 0;
    sums[t] = local;
    __syncthreads();
    for (int s = 1; s < 1024; s <<= 1) {
        int v = (t >= s) ? sums[t - s] : 0;
        __syncthreads();
        sums[t] += v;
        __syncthreads();
    }
    int run = (t == 0) ? 0 : sums[t - 1];
    for (int i = lo; i < hi; i++) {
        off[i] = run;
        run += (i < N) ? count[i] : 0;
    }
}

// hierarchical scan, phase 1: per-block sums (256 counters per block)
__global__ void __launch_bounds__(256) scan_part_kernel(
        const int* __restrict__ count, int* __restrict__ bsum, int N) {
    __shared__ int red[256];
    int t = threadIdx.x;
    int idx = blockIdx.x * 256 + t;
    red[t] = (idx < N) ? count[idx] : 0;
    __syncthreads();
    #pragma unroll
    for (int s = 128; s > 0; s >>= 1) {
        if (t < s) red[t] += red[t + s];
        __syncthreads();
    }
    if (t == 0) bsum[blockIdx.x] = red[0];
}

// hierarchical scan, phase 2: exclusive scan of <=1024 block sums; writes off[N] = total
__global__ void __launch_bounds__(1024) scan_top_kernel(
        const int* __restrict__ bsum, int* __restrict__ bpre,
        int* __restrict__ off, int N, int nblk) {
    __shared__ int s[1024];
    int t = threadIdx.x;
    int v = (t < nblk) ? bsum[t] : 0;
    s[t] = v;
    __syncthreads();
    for (int d = 1; d < 1024; d <<= 1) {
        int x = (t >= d) ? s[t - d] : 0;
        __syncthreads();
        s[t] += x;
        __syncthreads();
    }
    if (t < nblk) bpre[t] = s[t] - v;       // exclusive prefix of block sums
    if (t == 1023) off[N] = s[1023];        // total = E
}

// hierarchical scan, phase 3: block-local exclusive scan + block offset
__global__ void __launch_bounds__(256) scan_write_kernel(
        const int* __restrict__ count, const int* __restrict__ bpre,
        int* __restrict__ off, int N) {
    __shared__ int s[256];
    int t = threadIdx.x;
    int idx = blockIdx.x * 256 + t;
    int c = (idx < N) ? count[idx] : 0;
    s[t] = c;
    __syncthreads();
    for (int d = 1; d < 256; d <<= 1) {
        int x = (t >= d) ? s[t - d] : 0;
        __syncthreads();
        s[t] += x;
        __syncthreads();
    }
    if (idx < N) off[idx] = bpre[blockIdx.x] + s[t] - c;
}

__global__ void fill_kernel(const int* __restrict__ edst, const int* __restrict__ off,
                            int* __restrict__ cursor, int* __restrict__ list, int E) {
    int e = blockIdx.x * blockDim.x + threadIdx.x;
    if (e >= E) return;
    int d = edst[e];
    int p = atomicAdd(&cursor[d], 1);
    list[off[d] + p] = e;
}

// atomic-free CSR fill using precomputed rank. Stores src directly when no shifts.
__global__ void __launch_bounds__(256) permute_kernel(
        const int* __restrict__ edst, const int* __restrict__ esrc,
        const int* __restrict__ rank, const int* __restrict__ off,
        const int* __restrict__ flagp, int* __restrict__ list, int E) {
    int e = blockIdx.x * 256 + threadIdx.x;
    if (e >= E) return;
    int d = edst[e];
    int p = off[d] + rank[e];
    list[p] = (*flagp) ? e : esrc[e];
}

// ======== tier-1 conv: 4 nodes/wave; As/Ad from 10-type table At (L1); flag-gated shifts ==
__global__ void __launch_bounds__(256) conv_at_kernel(
        const float* __restrict__ pos, const int* __restrict__ batch,
        const int* __restrict__ esrc,
        const float* __restrict__ shifts, const float* __restrict__ cell,
        const int* __restrict__ A, const float* __restrict__ At,
        const float* __restrict__ tpwT, const float4* __restrict__ gtab,
        const int* __restrict__ flagp, const int* __restrict__ off,
        const int* __restrict__ list,
        float* __restrict__ out, int N) {
    __shared__ float s_stage[4][17 * STG];  // per-wave: rows q=0..16 x 64 cols (4 nodes x 16 slots)
    __shared__ float s_Z[4][288];           // per-wave: 4 nodes x 72 (u*9+i)
    __shared__ float s_M[4][388];           // per-wave: [l*128 + w*8 + u]
    __shared__ float s_Ad[4][32];           // per-wave: 4 nodes x 8

    const int tid = threadIdx.x, wv = tid >> 6, lane = tid & 63;
    const int k = lane >> 4, s = lane & 15;
    const int base = blockIdx.x * 16 + wv * 4;
    const int n = base + k;
    const bool nv = (n < N);

    const int FL = *flagp;   // wave-uniform

    int b0 = nv ? off[n] : 0;
    int b1 = nv ? off[n + 1] : 0;
    int deg = b1 - b0;

    if (s < 8) {
        int an = nv ? A[n] : 0;
        s_Ad[wv][k * 8 + s] = nv ? At[an * 8 + s] : 0.f;
    }

    float px = 0.f, py = 0.f, pz = 0.f;
    if (nv && deg > 0) { px = pos[n * 3 + 0]; py = pos[n * 3 + 1]; pz = pos[n * 3 + 2]; }

    // rounds = ceil(max deg over the wave's 4 nodes / 16)
    int md = deg;
    md = max(md, __shfl_xor(md, 16));
    md = max(md, __shfl_xor(md, 32));
    int nrnd = (md + 15) >> 4;

    float* st = s_stage[wv];

    // z-pairs: lane (k,s) owns pairs p = s + 16*j of node k (p = u*9 + i < 72)
    float z[5];
    const float4* ruP[5];
    const float4* riP[5];
    #pragma unroll
    for (int j = 0; j < 5; j++) {
        int p = s + 16 * j;
        int u = (p < 72) ? (p / 9) : 0;
        int i = (p < 72) ? (p - 9 * u) : 0;
        ruP[j] = (const float4*)(st + u * STG + k * 16);
        riP[j] = (const float4*)(st + (8 + i) * STG + k * 16);
        z[j] = 0.f;
    }

    #pragma unroll 1
    for (int rnd = 0; rnd < nrnd; rnd++) {
        int sl = (rnd << 4) + s;
        float As[8], gy[9];
        #pragma unroll
        for (int u = 0; u < 8; u++) As[u] = 0.f;
        #pragma unroll
        for (int i = 0; i < 9; i++) gy[i] = 0.f;
        if (sl < deg) {
            int v = list[b0 + sl];
            int src;
            float sv0 = 0.f, sv1 = 0.f, sv2 = 0.f;
            if (FL) {
                int e = v;
                src = esrc[e];
                float sh0 = shifts[e * 3 + 0], sh1 = shifts[e * 3 + 1], sh2 = shifts[e * 3 + 2];
                if (sh0 != 0.f || sh1 != 0.f || sh2 != 0.f) {
                    int g = batch[src];
                    const float* cg = cell + g * 9;
                    sv0 = sh0 * cg[0] + sh1 * cg[3] + sh2 * cg[6];
                    sv1 = sh0 * cg[1] + sh1 * cg[4] + sh2 * cg[7];
                    sv2 = sh0 * cg[2] + sh1 * cg[5] + sh2 * cg[8];
                }
            } else {
                src = v;   // permute stored esrc[e] directly
            }
            float vx = px - pos[src * 3 + 0] + sv0;   // dst = n
            float vy = py - pos[src * 3 + 1] + sv1;
            float vz = pz - pos[src * 3 + 2] + sv2;
            float len = sqrtf(vx * vx + vy * vy + vz * vz);
            float inv = 1.0f / fmaxf(len, 1e-8f);
            float nx = vx * inv, ny = vy * inv, nz = vz * inv;

            float tp = fminf(len * ((float)TSIZE / TMAXLEN), (float)(TSIZE - 1));
            int ti = (int)tp; if (ti > TSIZE - 2) ti = TSIZE - 2;
            float fr = tp - (float)ti;
            float4 ga = gtab[ti], gb = gtab[ti + 1];
            float g0 = ga.x + fr * (gb.x - ga.x);
            float g1 = ga.y + fr * (gb.y - ga.y);
            float g2 = ga.z + fr * (gb.z - ga.z);

            const float s3c = 1.7320508075688772f;
            const float s15 = 3.872983346207417f;
            const float s5h = 1.118033988749895f;
            gy[0] = g0;
            gy[1] = g1 * (s3c * nx); gy[2] = g1 * (s3c * ny); gy[3] = g1 * (s3c * nz);
            gy[4] = g2 * (s15 * nx * ny); gy[5] = g2 * (s15 * ny * nz);
            gy[6] = g2 * (s5h * (3.f * nz * nz - 1.f));
            gy[7] = g2 * (s15 * nx * nz); gy[8] = g2 * (0.5f * s15 * (nx * nx - ny * ny));

            int a = A[src];
            const float4* Ap = (const float4*)(At + a * 8);   // 320B table, L1-resident
            float4 A0 = Ap[0], A1 = Ap[1];
            As[0] = A0.x; As[1] = A0.y; As[2] = A0.z; As[3] = A0.w;
            As[4] = A1.x; As[5] = A1.y; As[6] = A1.z; As[7] = A1.w;
        }
        // stage transposed: row q, column = lane (conflict-free writes)
        #pragma unroll
        for (int u = 0; u < 8; u++) st[u * STG + lane] = As[u];
        #pragma unroll
        for (int i = 0; i < 9; i++) st[(8 + i) * STG + lane] = gy[i];
        __builtin_amdgcn_wave_barrier();
        #pragma unroll
        for (int j = 0; j < 5; j++) {
            if (j < 4 || s < 8) {
                #pragma unroll
                for (int c = 0; c < 4; c++) {
                    float4 a = ruP[j][c], b = riP[j][c];
                    z[j] += a.x * b.x + a.y * b.y + a.z * b.z + a.w * b.w;
                }
            }
        }
        __builtin_amdgcn_wave_barrier();
    }

    // publish Z: node k, element p = u*9+i
    #pragma unroll
    for (int j = 0; j < 5; j++)
        if (j < 4 || s < 8) s_Z[wv][k * 72 + s + 16 * j] = z[j];
    __builtin_amdgcn_wave_barrier();

    // k-invariant decode for M phase (6 elems/lane) and out phase (3 cols/lane)
    const float4* twp[6];
    int moff[6];
    #pragma unroll
    for (int t = 0; t < 6; t++) {
        int m = lane + (t << 6);
        int l = m >> 7, r = m & 127, u = r >> 4, w = r & 15;
        twp[t] = (const float4*)(tpwT + (l << 10) + (u << 7) + (w << 3));
        moff[t] = (l << 7) + (w << 3) + u;
    }
    int moffo[3], zoff[3];
    bool ov[3];
    #pragma unroll
    for (int t = 0; t < 3; t++) {
        int c = lane + (t << 6);
        ov[t] = (c < NCOL);
        int cc = ov[t] ? c : 0;
        int l, w, ii;
        if (cc < 16)      { l = 0; w = cc;            ii = 0; }
        else if (cc < 64) { l = 1; w = (cc - 16) / 3; ii = 1 + (cc - 16) % 3; }
        else              { l = 2; w = (cc - 64) / 5; ii = 4 + (cc - 64) % 5; }
        moffo[t] = (l << 7) + (w << 3);
        zoff[t] = ii;
    }

    float* M = s_M[wv];
    float* Zb = s_Z[wv];
    #pragma unroll 1
    for (int k2 = 0; k2 < 4; k2++) {
        int nk = base + k2;
        float Adk[8];
        #pragma unroll
        for (int v = 0; v < 8; v++) Adk[v] = s_Ad[wv][k2 * 8 + v];  // broadcast
        #pragma unroll
        for (int t = 0; t < 6; t++) {
            float4 wa = twp[t][0], wb = twp[t][1];
            M[moff[t]] = Adk[0] * wa.x + Adk[1] * wa.y + Adk[2] * wa.z + Adk[3] * wa.w
                       + Adk[4] * wb.x + Adk[5] * wb.y + Adk[6] * wb.z + Adk[7] * wb.w;
        }
        int degk = __shfl(deg, k2 * 16);
        __builtin_amdgcn_wave_barrier();
        if (nk < N) {
            float dinv = 1.0f / fmaxf((float)degk, 1.0f);
            const float* Zk = Zb + k2 * 72;
            #pragma unroll
            for (int t = 0; t < 3; t++) {
                if (ov[t]) {
                    const float4* mm = (const float4*)(M + moffo[t]);
                    float4 m0 = mm[0], m1 = mm[1];
                    int ii = zoff[t];
                    float val = m0.x * Zk[0 + ii]  + m0.y * Zk[9 + ii]
                              + m0.z * Zk[18 + ii] + m0.w * Zk[27 + ii]
                              + m1.x * Zk[36 + ii] + m1.y * Zk[45 + ii]
                              + m1.z * Zk[54 + ii] + m1.w * Zk[63 + ii];
                    out[(size_t)nk * NCOL + lane + (t << 6)] = val * dinv;
                }
            }
        }
        __builtin_amdgcn_wave_barrier();
    }
}

// ======== mid-tier (proven round-5) prologue: gate table + tpw transpose + node MLP =========
__global__ void __launch_bounds__(256) prologue_kernel(
        const int* __restrict__ A, const float* __restrict__ emb_table,
        const float* __restrict__ aw1, const float* __restrict__ ab1,
        const float* __restrict__ aw2, const float* __restrict__ ab2,
        const float* __restrict__ fw1, const float* __restrict__ fb1,
        const float* __restrict__ fw2, const float* __restrict__ fb2,
        const float* __restrict__ fw3, const float* __restrict__ fb3,
        const float* __restrict__ tpw,
        float* __restrict__ Ai, float4* __restrict__ tab,
        float* __restrict__ tpwT, int N) {
    __shared__ float s_w1[16 * 64];
    __shared__ float s_w2[64 * MUL];
    __shared__ float s_b1[64];
    __shared__ float s_b2[MUL];
    __shared__ float s_emb[10 * 16];

    int b = blockIdx.x;
    if (b < 32) {
        int i = b * 256 + threadIdx.x;
        if (i >= TSIZE) return;
        float len = (float)i * (TMAXLEN / TSIZE);
        float r = len * (17.0f / 5.0f);
        float h[64];
        #pragma unroll
        for (int j = 0; j < 64; j++) h[j] = fb1[j];
        #pragma unroll 1
        for (int k = 0; k < 16; k++) {
            float dk = r - (float)(k + 1);
            float ek = __expf(-dk * dk) * (4.0f / 1.12f);
            #pragma unroll
            for (int j = 0; j < 64; j++) h[j] += ek * fw1[k * 64 + j];
        }
        #pragma unroll
        for (int j = 0; j < 64; j++) h[j] = silu_f(h[j]);
        float g0 = fb3[0], g1 = fb3[3], g2 = fb3[9];
        #pragma unroll 1
        for (int j = 0; j < 64; j++) {
            float a = fb2[j];
            #pragma unroll
            for (int k = 0; k < 64; k++) a += h[k] * fw2[k * 64 + j];
            a = silu_f(a);
            g0 += a * fw3[j * 15 + 0];
            g1 += a * fw3[j * 15 + 3];
            g2 += a * fw3[j * 15 + 9];
        }
        tab[i] = make_float4(g0 * 0.125f, g1 * 0.125f, g2 * 0.125f, 0.f);
    } else if (b == 32) {
        const int pl[3] = {0, 3, 9};
        for (int i = threadIdx.x; i < 3072; i += 256) {
            int l = i >> 10, r = i & 1023;
            int u = r >> 7, v = (r >> 4) & 7, w = r & 15;
            tpwT[(l << 10) + (u << 7) + (w << 3) + v] = tpw[pl[l] * 1024 + r];
        }
    } else {
        for (int i = threadIdx.x; i < 16 * 64; i += 256) s_w1[i] = aw1[i];
        for (int i = threadIdx.x; i < 64 * MUL; i += 256) s_w2[i] = aw2[i];
        for (int i = threadIdx.x; i < 64; i += 256) s_b1[i] = ab1[i];
        for (int i = threadIdx.x; i < MUL; i += 256) s_b2[i] = ab2[i];
        for (int i = threadIdx.x; i < 160; i += 256) s_emb[i] = emb_table[i];
        __syncthreads();

        int n = (b - 33) * 256 + threadIdx.x;
        if (n >= N) return;
        int a = A[n];

        float h[64];
        #pragma unroll
        for (int j = 0; j < 64; j++) h[j] = s_b1[j];
        #pragma unroll 1
        for (int k = 0; k < 16; k++) {
            float ek = s_emb[a * 16 + k];
            #pragma unroll
            for (int j = 0; j < 64; j++) h[j] += ek * s_w1[k * 64 + j];
        }
        #pragma unroll
        for (int j = 0; j < 64; j++) h[j] = silu_f(h[j]);

        #pragma unroll 1
        for (int u = 0; u < MUL; u++) {
            float acc = s_b2[u];
            #pragma unroll
            for (int k = 0; k < 64; k++) acc += h[k] * s_w2[k * MUL + u];
            Ai[n * MUL + u] = acc;
        }
    }
}

// ---- mid-tier conv (proven round-5): 4 nodes/wave, Ai-based ----
__global__ void __launch_bounds__(256) conv_node4_kernel(
        const float* __restrict__ pos, const int* __restrict__ batch,
        const int* __restrict__ esrc,
        const float* __restrict__ shifts, const float* __restrict__ cell,
        const float* __restrict__ tpwT, const float4* __restrict__ gtab,
        const float* __restrict__ Ai, const int* __restrict__ off,
        const int* __restrict__ list,
        float* __restrict__ out, int N) {
    __shared__ float s_stage[4][17 * STG];
    __shared__ float s_Z[4][288];
    __shared__ float s_M[4][388];
    __shared__ float s_Ad[4][32];

    const int tid = threadIdx.x, wv = tid >> 6, lane = tid & 63;
    const int k = lane >> 4, s = lane & 15;
    const int base = blockIdx.x * 16 + wv * 4;
    const int n = base + k;
    const bool nv = (n < N);

    int b0 = nv ? off[n] : 0;
    int b1 = nv ? off[n + 1] : 0;
    int deg = b1 - b0;

    if (s < 8) s_Ad[wv][k * 8 + s] = nv ? Ai[(size_t)n * MUL + s] : 0.f;

    float px = 0.f, py = 0.f, pz = 0.f;
    if (nv && deg > 0) { px = pos[n * 3 + 0]; py = pos[n * 3 + 1]; pz = pos[n * 3 + 2]; }

    int md = deg;
    md = max(md, __shfl_xor(md, 16));
    md = max(md, __shfl_xor(md, 32));
    int nrnd = (md + 15) >> 4;

    float* st = s_stage[wv];

    float z[5];
    const float4* ruP[5];
    const float4* riP[5];
    #pragma unroll
    for (int j = 0; j < 5; j++) {
        int p = s + 16 * j;
        int u = (p < 72) ? (p / 9) : 0;
        int i = (p < 72) ? (p - 9 * u) : 0;
        ruP[j] = (const float4*)(st + u * STG + k * 16);
        riP[j] = (const float4*)(st + (8 + i) * STG + k * 16);
        z[j] = 0.f;
    }

    #pragma unroll 1
    for (int rnd = 0; rnd < nrnd; rnd++) {
        int sl = (rnd << 4) + s;
        float As[8], gy[9];
        #pragma unroll
        for (int u = 0; u < 8; u++) As[u] = 0.f;
        #pragma unroll
        for (int i = 0; i < 9; i++) gy[i] = 0.f;
        if (sl < deg) {
            int e = list[b0 + sl];
            float sh0 = shifts[e * 3 + 0], sh1 = shifts[e * 3 + 1], sh2 = shifts[e * 3 + 2];
            int src = esrc[e];
            float sv0 = 0.f, sv1 = 0.f, sv2 = 0.f;
            if (sh0 != 0.f || sh1 != 0.f || sh2 != 0.f) {
                int g = batch[src];
                const float* cg = cell + g * 9;
                sv0 = sh0 * cg[0] + sh1 * cg[3] + sh2 * cg[6];
                sv1 = sh0 * cg[1] + sh1 * cg[4] + sh2 * cg[7];
                sv2 = sh0 * cg[2] + sh1 * cg[5] + sh2 * cg[8];
            }
            float vx = px - pos[src * 3 + 0] + sv0;
            float vy = py - pos[src * 3 + 1] + sv1;
            float vz = pz - pos[src * 3 + 2] + sv2;
            float len = sqrtf(vx * vx + vy * vy + vz * vz);
            float inv = 1.0f / fmaxf(len, 1e-8f);
            float nx = vx * inv, ny = vy * inv, nz = vz * inv;

            float tp = fminf(len * ((float)TSIZE / TMAXLEN), (float)(TSIZE - 1));
            int ti = (int)tp; if (ti > TSIZE - 2) ti = TSIZE - 2;
            float fr = tp - (float)ti;
            float4 ga = gtab[ti], gb = gtab[ti + 1];
            float g0 = ga.x + fr * (gb.x - ga.x);
            float g1 = ga.y + fr * (gb.y - ga.y);
            float g2 = ga.z + fr * (gb.z - ga.z);

            const float s3c = 1.7320508075688772f;
            const float s15 = 3.872983346207417f;
            const float s5h = 1.118033988749895f;
            gy[0] = g0;
            gy[1] = g1 * (s3c * nx); gy[2] = g1 * (s3c * ny); gy[3] = g1 * (s3c * nz);
            gy[4] = g2 * (s15 * nx * ny); gy[5] = g2 * (s15 * ny * nz);
            gy[6] = g2 * (s5h * (3.f * nz * nz - 1.f));
            gy[7] = g2 * (s15 * nx * nz); gy[8] = g2 * (0.5f * s15 * (nx * nx - ny * ny));

            const float4* Ap = (const float4*)(Ai + (size_t)src * MUL);
            float4 A0 = Ap[0], A1 = Ap[1];
            As[0] = A0.x; As[1] = A0.y; As[2] = A0.z; As[3] = A0.w;
            As[4] = A1.x; As[5] = A1.y; As[6] = A1.z; As[7] = A1.w;
        }
        #pragma unroll
        for (int u = 0; u < 8; u++) st[u * STG + lane] = As[u];
        #pragma unroll
        for (int i = 0; i < 9; i++) st[(8 + i) * STG + lane] = gy[i];
        __builtin_amdgcn_wave_barrier();
        #pragma unroll
        for (int j = 0; j < 5; j++) {
            if (j < 4 || s < 8) {
                #pragma unroll
                for (int c = 0; c < 4; c++) {
                    float4 a = ruP[j][c], b = riP[j][c];
                    z[j] += a.x * b.x + a.y * b.y + a.z * b.z + a.w * b.w;
                }
            }
        }
        __builtin_amdgcn_wave_barrier();
    }

    #pragma unroll
    for (int j = 0; j < 5; j++)
        if (j < 4 || s < 8) s_Z[wv][k * 72 + s + 16 * j] = z[j];
    __builtin_amdgcn_wave_barrier();

    const float4* twp[6];
    int moff[6];
    #pragma unroll
    for (int t = 0; t < 6; t++) {
        int m = lane + (t << 6);
        int l = m >> 7, r = m & 127, u = r >> 4, w = r & 15;
        twp[t] = (const float4*)(tpwT + (l << 10) + (u << 7) + (w << 3));
        moff[t] = (l << 7) + (w << 3) + u;
    }
    int moffo[3], zoff[3];
    bool ov[3];
    #pragma unroll
    for (int t = 0; t < 3; t++) {
        int c = lane + (t << 6);
        ov[t] = (c < NCOL);
        int cc = ov[t] ? c : 0;
        int l, w, ii;
        if (cc < 16)      { l = 0; w = cc;            ii = 0; }
        else if (cc < 64) { l = 1; w = (cc - 16) / 3; ii = 1 + (cc - 16) % 3; }
        else              { l = 2; w = (cc - 64) / 5; ii = 4 + (cc - 64) % 5; }
        moffo[t] = (l << 7) + (w << 3);
        zoff[t] = ii;
    }

    float* M = s_M[wv];
    float* Zb = s_Z[wv];
    #pragma unroll 1
    for (int k2 = 0; k2 < 4; k2++) {
        int nk = base + k2;
        float Adk[8];
        #pragma unroll
        for (int v = 0; v < 8; v++) Adk[v] = s_Ad[wv][k2 * 8 + v];
        #pragma unroll
        for (int t = 0; t < 6; t++) {
            float4 wa = twp[t][0], wb = twp[t][1];
            M[moff[t]] = Adk[0] * wa.x + Adk[1] * wa.y + Adk[2] * wa.z + Adk[3] * wa.w
                       + Adk[4] * wb.x + Adk[5] * wb.y + Adk[6] * wb.z + Adk[7] * wb.w;
        }
        int degk = __shfl(deg, k2 * 16);
        __builtin_amdgcn_wave_barrier();
        if (nk < N) {
            float dinv = 1.0f / fmaxf((float)degk, 1.0f);
            const float* Zk = Zb + k2 * 72;
            #pragma unroll
            for (int t = 0; t < 3; t++) {
                if (ov[t]) {
                    const float4* mm = (const float4*)(M + moffo[t]);
                    float4 m0 = mm[0], m1 = mm[1];
                    int ii = zoff[t];
                    float val = m0.x * Zk[0 + ii]  + m0.y * Zk[9 + ii]
                              + m0.z * Zk[18 + ii] + m0.w * Zk[27 + ii]
                              + m1.x * Zk[36 + ii] + m1.y * Zk[45 + ii]
                              + m1.z * Zk[54 + ii] + m1.w * Zk[63 + ii];
                    out[(size_t)nk * NCOL + lane + (t << 6)] = val * dinv;
                }
            }
        }
        __builtin_amdgcn_wave_barrier();
    }
}

// ================= fallback (small ws): atomic path =================
__global__ void __launch_bounds__(256) edge_atomic_kernel(
        const float* __restrict__ pos, const int* __restrict__ batch,
        const int* __restrict__ esrc, const int* __restrict__ edst,
        const float* __restrict__ shifts, const float* __restrict__ cell,
        const float* __restrict__ fw1, const float* __restrict__ fb1,
        const float* __restrict__ fw2, const float* __restrict__ fb2,
        const float* __restrict__ fw3, const float* __restrict__ fb3,
        const float* __restrict__ tpw,
        const float* __restrict__ Ai,
        float* __restrict__ out, float* __restrict__ deg, int E) {
    __shared__ float s_w1[16 * 64];
    __shared__ float s_w2[64 * 64];
    __shared__ float s_w3[64 * 3];
    __shared__ float s_b1[64];
    __shared__ float s_b2[64];
    __shared__ float s_b3[3];
    __shared__ float s_tpw[3 * 1024];
    for (int i = threadIdx.x; i < 1024; i += blockDim.x) s_w1[i] = fw1[i];
    for (int i = threadIdx.x; i < 4096; i += blockDim.x) s_w2[i] = fw2[i];
    for (int i = threadIdx.x; i < 64; i += blockDim.x) { s_b1[i] = fb1[i]; s_b2[i] = fb2[i]; }
    for (int i = threadIdx.x; i < 192; i += blockDim.x) {
        int j = i / 3, c = i - 3 * j;
        int cc = (c == 0) ? 0 : ((c == 1) ? 3 : 9);
        s_w3[i] = fw3[j * 15 + cc];
    }
    if (threadIdx.x < 3) {
        int cc = (threadIdx.x == 0) ? 0 : ((threadIdx.x == 1) ? 3 : 9);
        s_b3[threadIdx.x] = fb3[cc];
    }
    for (int i = threadIdx.x; i < 3 * 1024; i += blockDim.x) {
        int l = i >> 10, r = i & 1023;
        int p = (l == 0) ? 0 : ((l == 1) ? 3 : 9);
        s_tpw[i] = tpw[p * 1024 + r];
    }
    __syncthreads();
    int e = blockIdx.x * blockDim.x + threadIdx.x;
    if (e >= E) return;
    int s = esrc[e], d = edst[e];
    int g = batch[s];
    float sh0 = shifts[e * 3 + 0], sh1 = shifts[e * 3 + 1], sh2 = shifts[e * 3 + 2];
    const float* cg = cell + g * 9;
    float sv0 = sh0 * cg[0] + sh1 * cg[3] + sh2 * cg[6];
    float sv1 = sh0 * cg[1] + sh1 * cg[4] + sh2 * cg[7];
    float sv2 = sh0 * cg[2] + sh1 * cg[5] + sh2 * cg[8];
    float vx = pos[d * 3 + 0] - pos[s * 3 + 0] + sv0;
    float vy = pos[d * 3 + 1] - pos[s * 3 + 1] + sv1;
    float vz = pos[d * 3 + 2] - pos[s * 3 + 2] + sv2;
    float len = sqrtf(vx * vx + vy * vy + vz * vz);
    float inv = 1.0f / fmaxf(len, 1e-8f);
    float nx = vx * inv, ny = vy * inv, nz = vz * inv;
    float r = len * (17.0f / 5.0f);
    float h[64];
    #pragma unroll
    for (int j = 0; j < 64; j++) h[j] = s_b1[j];
    #pragma unroll 1
    for (int k = 0; k < 16; k++) {
        float dk = r - (float)(k + 1);
        float ek = __expf(-dk * dk) * (4.0f / 1.12f);
        #pragma unroll
        for (int j = 0; j < 64; j++) h[j] += ek * s_w1[k * 64 + j];
    }
    #pragma unroll
    for (int j = 0; j < 64; j++) h[j] = silu_f(h[j]);
    float g0 = s_b3[0], g1 = s_b3[1], g2 = s_b3[2];
    #pragma unroll 2
    for (int j = 0; j < 64; j++) {
        float a = s_b2[j];
        #pragma unroll
        for (int k = 0; k < 64; k++) a += h[k] * s_w2[k * 64 + j];
        a = silu_f(a);
        g0 += a * s_w3[j * 3 + 0];
        g1 += a * s_w3[j * 3 + 1];
        g2 += a * s_w3[j * 3 + 2];
    }
    g0 *= 0.125f; g1 *= 0.125f; g2 *= 0.125f;
    float t0[16], t1[16], t2[16];
    #pragma unroll
    for (int w = 0; w < 16; w++) { t0[w] = 0.f; t1[w] = 0.f; t2[w] = 0.f; }
    int s8 = s * MUL, d8 = d * MUL;
    float Ad[8];
    #pragma unroll
    for (int v = 0; v < 8; v++) Ad[v] = Ai[d8 + v];
    #pragma unroll 1
    for (int u = 0; u < 8; u++) {
        float asu = Ai[s8 + u];
        int offp = u * 128;
        #pragma unroll
        for (int v = 0; v < 8; v++) {
            float p = asu * Ad[v];
            int o2 = offp + v * 16;
            #pragma unroll
            for (int w = 0; w < 16; w++) {
                t0[w] += p * s_tpw[o2 + w];
                t1[w] += p * s_tpw[1024 + o2 + w];
                t2[w] += p * s_tpw[2048 + o2 + w];
            }
        }
    }
    #pragma unroll
    for (int w = 0; w < 16; w++) { t0[w] *= g0; t1[w] *= g1; t2[w] *= g2; }
    const float s3 = 1.7320508075688772f;
    const float s15 = 3.872983346207417f;
    const float s5h = 1.118033988749895f;
    float y1_[3] = { s3 * nx, s3 * ny, s3 * nz };
    float y2_[5] = { s15 * nx * ny, s15 * ny * nz, s5h * (3.f * nz * nz - 1.f),
                     s15 * nx * nz, 0.5f * s15 * (nx * nx - ny * ny) };
    float* o = out + (size_t)d * NCOL;
    #pragma unroll
    for (int w = 0; w < 16; w++) atomicAdd(o + w, t0[w]);
    #pragma unroll
    for (int w = 0; w < 16; w++)
        #pragma unroll
        for (int i = 0; i < 3; i++) atomicAdd(o + 16 + w * 3 + i, t1[w] * y1_[i]);
    #pragma unroll
    for (int w = 0; w < 16; w++)
        #pragma unroll
        for (int i = 0; i < 5; i++) atomicAdd(o + 64 + w * 5 + i, t2[w] * y2_[i]);
    atomicAdd(deg + d, 1.0f);
}

__global__ void finalize_kernel(float* __restrict__ out, const float* __restrict__ deg, int total) {
    int idx = blockIdx.x * blockDim.x + threadIdx.x;
    if (idx >= total) return;
    int n = idx / NCOL;
    out[idx] = out[idx] / fmaxf(deg[n], 1.0f);
}

extern "C" void kernel_launch(void* const* d_in, const int* in_sizes, int n_in,
                              void* d_out, int out_size, void* d_ws, size_t ws_size,
                              hipStream_t stream) {
    const float* pos    = (const float*)d_in[0];
    const int*   A      = (const int*)d_in[1];
    const int*   batch  = (const int*)d_in[2];
    const int*   esrc   = (const int*)d_in[3];
    const int*   edst   = (const int*)d_in[4];
    const float* shifts = (const float*)d_in[5];
    const float* cellp  = (const float*)d_in[6];
    const float* embt   = (const float*)d_in[7];
    const float* aw1    = (const float*)d_in[8];
    const float* ab1    = (const float*)d_in[9];
    const float* aw2    = (const float*)d_in[10];
    const float* ab2    = (const float*)d_in[11];
    const float* fw1    = (const float*)d_in[12];
    const float* fb1    = (const float*)d_in[13];
    const float* fw2    = (const float*)d_in[14];
    const float* fb2    = (const float*)d_in[15];
    const float* fw3    = (const float*)d_in[16];
    const float* fb3    = (const float*)d_in[17];
    const float* tpw    = (const float*)d_in[18];

    int N = in_sizes[1];
    int E = in_sizes[3];
    float* out = (float*)d_out;

    int nblk = (N + 255) / 256;
    int eblk = (E + 255) / 256;

    // NEW tier: count[N] | flag[1] | off[N+1] | rank[E] | list[E] | gtab | tpwT | At[80] | bsum | bpre
    size_t need_new = ((size_t)N + 1 + (size_t)(N + 1) + (size_t)E * 2) * 4
                    + (size_t)TSIZE * 16 + 3072 * 4 + 320 + 8192 + 768;
    // mid tier (round-5 proven): Ai | count | cursor | off | list | gtab | tpwT | bsum | bpre
    size_t need_mid = (size_t)N * 32 + (size_t)N * 8 + (size_t)(N + 1) * 4
                    + (size_t)E * 4 + (size_t)TSIZE * 16 + 3072 * 4 + 8192 + 1024;

    if (ws_size >= need_new && nblk <= 1024) {
        int*    count = (int*)d_ws;
        int*    flag  = count + N;
        int*    off   = flag + 1;
        int*    rank  = off + (N + 1);
        int*    list  = rank + E;
        float4* gtab  = (float4*)(((uintptr_t)(list + E) + 255) & ~(uintptr_t)255);
        float*  tpwT  = (float*)(gtab + TSIZE);
        float*  At    = tpwT + 3072;
        int*    bsum  = (int*)(At + 80);
        int*    bpre  = bsum + 1024;

        hipMemsetAsync(count, 0, ((size_t)N + 1) * sizeof(int), stream);  // count + flag

        front_kernel<<<GBLK + 1 + eblk, 256, 0, stream>>>(
            edst, shifts, embt, aw1, ab1, aw2, ab2,
            fw1, fb1, fw2, fb2, fw3, fb3, tpw,
            count, rank, flag, At, gtab, tpwT, E);

        scan_part_kernel<<<nblk, 256, 0, stream>>>(count, bsum, N);
        scan_top_kernel<<<1, 1024, 0, stream>>>(bsum, bpre, off, N, nblk);
        scan_write_kernel<<<nblk, 256, 0, stream>>>(count, bpre, off, N);

        permute_kernel<<<eblk, 256, 0, stream>>>(edst, esrc, rank, off, flag, list, E);

        conv_at_kernel<<<(N + 15) / 16, 256, 0, stream>>>(
            pos, batch, esrc, shifts, cellp, A, At, tpwT, gtab, flag, off, list, out, N);
    } else if (ws_size >= need_mid) {
        float*  Ai     = (float*)d_ws;
        int*    count  = (int*)(Ai + (size_t)N * MUL);
        int*    cursor = count + N;
        int*    off    = cursor + N;
        int*    list   = off + (N + 1);
        float4* gtab   = (float4*)(((uintptr_t)(list + E) + 255) & ~(uintptr_t)255);
        float*  tpwT   = (float*)(gtab + TSIZE);
        int*    bsum   = (int*)(tpwT + 3072);
        int*    bpre   = bsum + 1024;

        hipMemsetAsync(count, 0, (size_t)N * 2 * sizeof(int), stream);  // count + cursor

        prologue_kernel<<<33 + nblk, 256, 0, stream>>>(
            A, embt, aw1, ab1, aw2, ab2, fw1, fb1, fw2, fb2, fw3, fb3,
            tpw, Ai, gtab, tpwT, N);
        count_kernel<<<eblk, 256, 0, stream>>>(edst, count, E);

        if (nblk <= 1024) {
            scan_part_kernel<<<nblk, 256, 0, stream>>>(count, bsum, N);
            scan_top_kernel<<<1, 1024, 0, stream>>>(bsum, bpre, off, N, nblk);
            scan_write_kernel<<<nblk, 256, 0, stream>>>(count, bpre, off, N);
        } else {
            scan_kernel<<<1, 1024, 0, stream>>>(count, off, N);
        }

        fill_kernel<<<eblk, 256, 0, stream>>>(edst, off, cursor, list, E);

        conv_node4_kernel<<<(N + 15) / 16, 256, 0, stream>>>(
            pos, batch, esrc, shifts, cellp, tpwT, gtab, Ai, off, list, out, N);
    } else {
        float* Ai  = (float*)d_ws;
        float* deg = Ai + (size_t)N * MUL;
        hipMemsetAsync(out, 0, (size_t)out_size * sizeof(float), stream);
        hipMemsetAsync(deg, 0, (size_t)N * sizeof(float), stream);
        node_mlp_kernel<<<(N + 255) / 256, 256, 0, stream>>>(A, embt, aw1, ab1, aw2, ab2, Ai, N);
        edge_atomic_kernel<<<eblk, 256, 0, stream>>>(
            pos, batch, esrc, edst, shifts, cellp,
            fw1, fb1, fw2, fb2, fw3, fb3, tpw, Ai, out, deg, E);
        int total = N * NCOL;
        finalize_kernel<<<(total + 255) / 256, 256, 0, stream>>>(out, deg, total);
    }
}

// Round 9
// 199.754 us; speedup vs baseline: 1.2790x; 1.0009x over previous
//
#include <hip/hip_runtime.h>
#include <hip/hip_bf16.h>
#include <math.h>

#define MUL 8
#define NCOL 144   // 16*(1+3+5)
#define TSIZE 8192
#define TMAXLEN 8.0f
#define STG 68     // stage row stride (floats): 64 data + 4 pad, breaks 256B bank aliasing
#define GBLK 512   // gate-table blocks in front_kernel
#define SRCMASK ((1 << 27) - 1)   // list packing: src | (atomtype << 27) when no shifts

__device__ __forceinline__ float silu_f(float x) { return x / (1.0f + __expf(-x)); }

// ---------------- node MLP -> Ai[N][8] (standalone: used by fallback tier) ----------------
__global__ void node_mlp_kernel(const int* __restrict__ A,
                                const float* __restrict__ emb_table,
                                const float* __restrict__ w1,
                                const float* __restrict__ b1,
                                const float* __restrict__ w2,
                                const float* __restrict__ b2,
                                float* __restrict__ Ai, int N) {
    __shared__ float s_w1[16 * 64];
    __shared__ float s_w2[64 * MUL];
    __shared__ float s_b1[64];
    __shared__ float s_b2[MUL];
    __shared__ float s_emb[10 * 16];
    for (int i = threadIdx.x; i < 16 * 64; i += blockDim.x) s_w1[i] = w1[i];
    for (int i = threadIdx.x; i < 64 * MUL; i += blockDim.x) s_w2[i] = w2[i];
    for (int i = threadIdx.x; i < 64; i += blockDim.x) s_b1[i] = b1[i];
    for (int i = threadIdx.x; i < MUL; i += blockDim.x) s_b2[i] = b2[i];
    for (int i = threadIdx.x; i < 160; i += blockDim.x) s_emb[i] = emb_table[i];
    __syncthreads();

    int n = blockIdx.x * blockDim.x + threadIdx.x;
    if (n >= N) return;
    int a = A[n];

    float h[64];
    #pragma unroll
    for (int j = 0; j < 64; j++) h[j] = s_b1[j];
    #pragma unroll 1
    for (int k = 0; k < 16; k++) {
        float ek = s_emb[a * 16 + k];
        #pragma unroll
        for (int j = 0; j < 64; j++) h[j] += ek * s_w1[k * 64 + j];
    }
    #pragma unroll
    for (int j = 0; j < 64; j++) h[j] = silu_f(h[j]);

    #pragma unroll 1
    for (int u = 0; u < MUL; u++) {
        float acc = s_b2[u];
        #pragma unroll
        for (int k = 0; k < 64; k++) acc += h[k] * s_w2[k * MUL + u];
        Ai[n * MUL + u] = acc;
    }
}

// ======== tier-1 front kernel: wave-cooperative gate table + transpose/At + edge pass ========
__global__ void __launch_bounds__(256) front_kernel(
        const int* __restrict__ edst, const float* __restrict__ shifts,
        const float* __restrict__ emb_table,
        const float* __restrict__ aw1, const float* __restrict__ ab1,
        const float* __restrict__ aw2, const float* __restrict__ ab2,
        const float* __restrict__ fw1, const float* __restrict__ fb1,
        const float* __restrict__ fw2, const float* __restrict__ fb2,
        const float* __restrict__ fw3, const float* __restrict__ fb3,
        const float* __restrict__ tpw,
        int* __restrict__ count, int* __restrict__ rank, int* __restrict__ flag,
        float* __restrict__ At, float4* __restrict__ tab,
        float* __restrict__ tpwT, int E) {
    const int b = blockIdx.x;
    const int lane = threadIdx.x & 63, wv = threadIdx.x >> 6;

    if (b < GBLK) {
        // ---- gate table, wave-cooperative: lane j owns column j of the 64-wide MLP ----
        int gw = b * 4 + wv;
        #pragma unroll 1
        for (int e = gw; e < TSIZE; e += GBLK * 4) {
            float len = (float)e * (TMAXLEN / TSIZE);
            float r = len * (17.0f / 5.0f);
            float h = fb1[lane];
            #pragma unroll
            for (int k = 0; k < 16; k++) {
                float dk = r - (float)(k + 1);
                float ek = __expf(-dk * dk) * (4.0f / 1.12f);
                h += ek * fw1[k * 64 + lane];
            }
            h = silu_f(h);
            float a = fb2[lane];
            #pragma unroll
            for (int k = 0; k < 64; k++) a += __shfl(h, k) * fw2[k * 64 + lane];
            a = silu_f(a);
            float g0 = a * fw3[lane * 15 + 0];
            float g1 = a * fw3[lane * 15 + 3];
            float g2 = a * fw3[lane * 15 + 9];
            #pragma unroll
            for (int off = 32; off > 0; off >>= 1) {
                g0 += __shfl_xor(g0, off);
                g1 += __shfl_xor(g1, off);
                g2 += __shfl_xor(g2, off);
            }
            if (lane == 0)
                tab[e] = make_float4((fb3[0] + g0) * 0.125f,
                                     (fb3[3] + g1) * 0.125f,
                                     (fb3[9] + g2) * 0.125f, 0.f);
        }
    } else if (b == GBLK) {
        // ---- tpw transpose (proven layout) ----
        const int pl[3] = {0, 3, 9};
        for (int i = threadIdx.x; i < 3072; i += 256) {
            int l = i >> 10, r = i & 1023;
            int u = r >> 7, v = (r >> 4) & 7, w = r & 15;
            tpwT[(l << 10) + (u << 7) + (w << 3) + v] = tpw[pl[l] * 1024 + r];
        }
        // ---- At[10][8], wave-cooperative: one type per wave per pass ----
        #pragma unroll 1
        for (int ty = wv; ty < 10; ty += 4) {
            float h = ab1[lane];
            #pragma unroll
            for (int k = 0; k < 16; k++) h += emb_table[ty * 16 + k] * aw1[k * 64 + lane];
            h = silu_f(h);
            float p[8];
            #pragma unroll
            for (int u = 0; u < 8; u++) p[u] = h * aw2[lane * MUL + u];
            #pragma unroll
            for (int off = 32; off > 0; off >>= 1)
                #pragma unroll
                for (int u = 0; u < 8; u++) p[u] += __shfl_xor(p[u], off);
            if (lane == 0) {
                #pragma unroll
                for (int u = 0; u < 8; u++) At[ty * MUL + u] = ab2[u] + p[u];
            }
        }
    } else {
        // ---- edge pass: count + rank + anyShift flag ----
        int e = (b - GBLK - 1) * 256 + threadIdx.x;
        bool nz = false;
        if (e < E) {
            int d = edst[e];
            float sh0 = shifts[e * 3 + 0], sh1 = shifts[e * 3 + 1], sh2 = shifts[e * 3 + 2];
            nz = (sh0 != 0.f) || (sh1 != 0.f) || (sh2 != 0.f);
            rank[e] = atomicAdd(&count[d], 1);
        }
        if (__ballot(nz)) {
            if (lane == 0) atomicOr(flag, 1);
        }
    }
}

// ---------------- CSR build (mid-tier helpers, proven) ----------------
__global__ void count_kernel(const int* __restrict__ edst, int* __restrict__ count, int E) {
    int e = blockIdx.x * blockDim.x + threadIdx.x;
    if (e < E) atomicAdd(&count[edst[e]], 1);
}

// single-block scan (fallback for huge N)
__global__ void scan_kernel(const int* __restrict__ count, int* __restrict__ off, int N) {
    __shared__ int sums[1024];
    int L = N + 1;
    int chunk = (L + 1023) / 1024;
    int t = threadIdx.x;
    int lo = t * chunk;
    int hi = lo + chunk; if (hi > L) hi = L;
    int local = 0;
    for (int i = lo; i < hi; i++) local += (i < N) ? count[i] : 0;
    sums[t] = local;
    __syncthreads();
    for (int s = 1; s < 1024; s <<= 1) {
        int v = (t >= s) ? sums[t - s] : 0;
        __syncthreads();
        sums[t] += v;
        __syncthreads();
    }
    int run = (t == 0) ? 0 : sums[t - 1];
    for (int i = lo; i < hi; i++) {
        off[i] = run;
        run += (i < N) ? count[i] : 0;
    }
}

// hierarchical scan, phase 1: per-block sums (256 counters per block)
__global__ void __launch_bounds__(256) scan_part_kernel(
        const int* __restrict__ count, int* __restrict__ bsum, int N) {
    __shared__ int red[256];
    int t = threadIdx.x;
    int idx = blockIdx.x * 256 + t;
    red[t] = (idx < N) ? count[idx] : 0;
    __syncthreads();
    #pragma unroll
    for (int s = 128; s > 0; s >>= 1) {
        if (t < s) red[t] += red[t + s];
        __syncthreads();
    }
    if (t == 0) bsum[blockIdx.x] = red[0];
}

// hierarchical scan, phase 2: exclusive scan of <=1024 block sums; writes off[N] = total
__global__ void __launch_bounds__(1024) scan_top_kernel(
        const int* __restrict__ bsum, int* __restrict__ bpre,
        int* __restrict__ off, int N, int nblk) {
    __shared__ int s[1024];
    int t = threadIdx.x;
    int v = (t < nblk) ? bsum[t] : 0;
    s[t] = v;
    __syncthreads();
    for (int d = 1; d < 1024; d <<= 1) {
        int x = (t >= d) ? s[t - d] : 0;
        __syncthreads();
        s[t] += x;
        __syncthreads();
    }
    if (t < nblk) bpre[t] = s[t] - v;       // exclusive prefix of block sums
    if (t == 1023) off[N] = s[1023];        // total = E
}

// hierarchical scan, phase 3: block-local exclusive scan + block offset
__global__ void __launch_bounds__(256) scan_write_kernel(
        const int* __restrict__ count, const int* __restrict__ bpre,
        int* __restrict__ off, int N) {
    __shared__ int s[256];
    int t = threadIdx.x;
    int idx = blockIdx.x * 256 + t;
    int c = (idx < N) ? count[idx] : 0;
    s[t] = c;
    __syncthreads();
    for (int d = 1; d < 256; d <<= 1) {
        int x = (t >= d) ? s[t - d] : 0;
        __syncthreads();
        s[t] += x;
        __syncthreads();
    }
    if (idx < N) off[idx] = bpre[blockIdx.x] + s[t] - c;
}

__global__ void fill_kernel(const int* __restrict__ edst, const int* __restrict__ off,
                            int* __restrict__ cursor, int* __restrict__ list, int E) {
    int e = blockIdx.x * blockDim.x + threadIdx.x;
    if (e >= E) return;
    int d = edst[e];
    int p = atomicAdd(&cursor[d], 1);
    list[off[d] + p] = e;
}

// atomic-free CSR fill using precomputed rank. When no shifts exist, stores
// src | (A[src]<<27) so conv skips the dependent A gather entirely.
__global__ void __launch_bounds__(256) permute_kernel(
        const int* __restrict__ edst, const int* __restrict__ esrc,
        const int* __restrict__ A,
        const int* __restrict__ rank, const int* __restrict__ off,
        const int* __restrict__ flagp, int* __restrict__ list, int E) {
    int e = blockIdx.x * 256 + threadIdx.x;
    if (e >= E) return;
    int d = edst[e];
    int p = off[d] + rank[e];
    if (*flagp) {
        list[p] = e;
    } else {
        int s = esrc[e];
        list[p] = s | (A[s] << 27);
    }
}

// ======== tier-1 conv: 4 nodes/wave; LDS union (stage overlays Z/M); packed list ==========
__global__ void __launch_bounds__(256) conv_at_kernel(
        const float* __restrict__ pos, const int* __restrict__ batch,
        const int* __restrict__ esrc,
        const float* __restrict__ shifts, const float* __restrict__ cell,
        const int* __restrict__ A, const float* __restrict__ At,
        const float* __restrict__ tpwT, const float4* __restrict__ gtab,
        const int* __restrict__ flagp, const int* __restrict__ off,
        const int* __restrict__ list,
        float* __restrict__ out, int N) {
    // stage (rounds loop) is dead before Z/M (epilogue) become live -> union them.
    // Same-wave LDS ops execute in order; the k2 loop already relied on this for M reuse.
    struct __align__(16) WScr {
        union {
            float stage[17 * STG];                    // 4624 B
            struct { float Z[288]; float M[388]; } zm; // 2704 B (Z 16B-aligned, M at 1152B)
        };
    };
    __shared__ WScr s_scr[4];       // per-wave
    __shared__ float s_Ad[4][32];   // per-wave: 4 nodes x 8 (live whole kernel)

    const int tid = threadIdx.x, wv = tid >> 6, lane = tid & 63;
    const int k = lane >> 4, s = lane & 15;
    const int base = blockIdx.x * 16 + wv * 4;
    const int n = base + k;
    const bool nv = (n < N);

    const int FL = *flagp;   // wave-uniform

    int b0 = nv ? off[n] : 0;
    int b1 = nv ? off[n + 1] : 0;
    int deg = b1 - b0;

    if (s < 8) {
        int an = nv ? A[n] : 0;
        s_Ad[wv][k * 8 + s] = nv ? At[an * 8 + s] : 0.f;
    }

    float px = 0.f, py = 0.f, pz = 0.f;
    if (nv && deg > 0) { px = pos[n * 3 + 0]; py = pos[n * 3 + 1]; pz = pos[n * 3 + 2]; }

    // rounds = ceil(max deg over the wave's 4 nodes / 16)
    int md = deg;
    md = max(md, __shfl_xor(md, 16));
    md = max(md, __shfl_xor(md, 32));
    int nrnd = (md + 15) >> 4;

    float* st = s_scr[wv].stage;

    // z-pairs: lane (k,s) owns pairs p = s + 16*j of node k (p = u*9 + i < 72)
    float z[5];
    const float4* ruP[5];
    const float4* riP[5];
    #pragma unroll
    for (int j = 0; j < 5; j++) {
        int p = s + 16 * j;
        int u = (p < 72) ? (p / 9) : 0;
        int i = (p < 72) ? (p - 9 * u) : 0;
        ruP[j] = (const float4*)(st + u * STG + k * 16);
        riP[j] = (const float4*)(st + (8 + i) * STG + k * 16);
        z[j] = 0.f;
    }

    #pragma unroll 1
    for (int rnd = 0; rnd < nrnd; rnd++) {
        int sl = (rnd << 4) + s;
        float As[8], gy[9];
        #pragma unroll
        for (int u = 0; u < 8; u++) As[u] = 0.f;
        #pragma unroll
        for (int i = 0; i < 9; i++) gy[i] = 0.f;
        if (sl < deg) {
            int v = list[b0 + sl];
            int src, a;
            float sv0 = 0.f, sv1 = 0.f, sv2 = 0.f;
            if (FL) {
                int e = v;
                src = esrc[e];
                a = A[src];
                float sh0 = shifts[e * 3 + 0], sh1 = shifts[e * 3 + 1], sh2 = shifts[e * 3 + 2];
                if (sh0 != 0.f || sh1 != 0.f || sh2 != 0.f) {
                    int g = batch[src];
                    const float* cg = cell + g * 9;
                    sv0 = sh0 * cg[0] + sh1 * cg[3] + sh2 * cg[6];
                    sv1 = sh0 * cg[1] + sh1 * cg[4] + sh2 * cg[7];
                    sv2 = sh0 * cg[2] + sh1 * cg[5] + sh2 * cg[8];
                }
            } else {
                src = v & SRCMASK;   // permute packed src | (A[src]<<27)
                a = v >> 27;
            }
            float vx = px - pos[src * 3 + 0] + sv0;   // dst = n
            float vy = py - pos[src * 3 + 1] + sv1;
            float vz = pz - pos[src * 3 + 2] + sv2;
            float len = sqrtf(vx * vx + vy * vy + vz * vz);
            float inv = 1.0f / fmaxf(len, 1e-8f);
            float nx = vx * inv, ny = vy * inv, nz = vz * inv;

            float tp = fminf(len * ((float)TSIZE / TMAXLEN), (float)(TSIZE - 1));
            int ti = (int)tp; if (ti > TSIZE - 2) ti = TSIZE - 2;
            float fr = tp - (float)ti;
            float4 ga = gtab[ti], gb = gtab[ti + 1];
            float g0 = ga.x + fr * (gb.x - ga.x);
            float g1 = ga.y + fr * (gb.y - ga.y);
            float g2 = ga.z + fr * (gb.z - ga.z);

            const float s3c = 1.7320508075688772f;
            const float s15 = 3.872983346207417f;
            const float s5h = 1.118033988749895f;
            gy[0] = g0;
            gy[1] = g1 * (s3c * nx); gy[2] = g1 * (s3c * ny); gy[3] = g1 * (s3c * nz);
            gy[4] = g2 * (s15 * nx * ny); gy[5] = g2 * (s15 * ny * nz);
            gy[6] = g2 * (s5h * (3.f * nz * nz - 1.f));
            gy[7] = g2 * (s15 * nx * nz); gy[8] = g2 * (0.5f * s15 * (nx * nx - ny * ny));

            const float4* Ap = (const float4*)(At + a * 8);   // 320B table, L1-resident
            float4 A0 = Ap[0], A1 = Ap[1];
            As[0] = A0.x; As[1] = A0.y; As[2] = A0.z; As[3] = A0.w;
            As[4] = A1.x; As[5] = A1.y; As[6] = A1.z; As[7] = A1.w;
        }
        // stage transposed: row q, column = lane (conflict-free writes)
        #pragma unroll
        for (int u = 0; u < 8; u++) st[u * STG + lane] = As[u];
        #pragma unroll
        for (int i = 0; i < 9; i++) st[(8 + i) * STG + lane] = gy[i];
        __builtin_amdgcn_wave_barrier();
        #pragma unroll
        for (int j = 0; j < 5; j++) {
            if (j < 4 || s < 8) {
                #pragma unroll
                for (int c = 0; c < 4; c++) {
                    float4 a = ruP[j][c], b = riP[j][c];
                    z[j] += a.x * b.x + a.y * b.y + a.z * b.z + a.w * b.w;
                }
            }
        }
        __builtin_amdgcn_wave_barrier();
    }

    // publish Z (overlays dead stage region; per-wave in-order LDS + data dep make this safe)
    float* Zb = s_scr[wv].zm.Z;
    #pragma unroll
    for (int j = 0; j < 5; j++)
        if (j < 4 || s < 8) Zb[k * 72 + s + 16 * j] = z[j];
    __builtin_amdgcn_wave_barrier();

    // k-invariant decode for M phase (6 elems/lane) and out phase (3 cols/lane)
    const float4* twp[6];
    int moff[6];
    #pragma unroll
    for (int t = 0; t < 6; t++) {
        int m = lane + (t << 6);
        int l = m >> 7, r = m & 127, u = r >> 4, w = r & 15;
        twp[t] = (const float4*)(tpwT + (l << 10) + (u << 7) + (w << 3));
        moff[t] = (l << 7) + (w << 3) + u;
    }
    int moffo[3], zoff[3];
    bool ov[3];
    #pragma unroll
    for (int t = 0; t < 3; t++) {
        int c = lane + (t << 6);
        ov[t] = (c < NCOL);
        int cc = ov[t] ? c : 0;
        int l, w, ii;
        if (cc < 16)      { l = 0; w = cc;            ii = 0; }
        else if (cc < 64) { l = 1; w = (cc - 16) / 3; ii = 1 + (cc - 16) % 3; }
        else              { l = 2; w = (cc - 64) / 5; ii = 4 + (cc - 64) % 5; }
        moffo[t] = (l << 7) + (w << 3);
        zoff[t] = ii;
    }

    float* M = s_scr[wv].zm.M;
    #pragma unroll 1
    for (int k2 = 0; k2 < 4; k2++) {
        int nk = base + k2;
        float Adk[8];
        #pragma unroll
        for (int v = 0; v < 8; v++) Adk[v] = s_Ad[wv][k2 * 8 + v];  // broadcast
        #pragma unroll
        for (int t = 0; t < 6; t++) {
            float4 wa = twp[t][0], wb = twp[t][1];
            M[moff[t]] = Adk[0] * wa.x + Adk[1] * wa.y + Adk[2] * wa.z + Adk[3] * wa.w
                       + Adk[4] * wb.x + Adk[5] * wb.y + Adk[6] * wb.z + Adk[7] * wb.w;
        }
        int degk = __shfl(deg, k2 * 16);
        __builtin_amdgcn_wave_barrier();
        if (nk < N) {
            float dinv = 1.0f / fmaxf((float)degk, 1.0f);
            const float* Zk = Zb + k2 * 72;
            #pragma unroll
            for (int t = 0; t < 3; t++) {
                if (ov[t]) {
                    const float4* mm = (const float4*)(M + moffo[t]);
                    float4 m0 = mm[0], m1 = mm[1];
                    int ii = zoff[t];
                    float val = m0.x * Zk[0 + ii]  + m0.y * Zk[9 + ii]
                              + m0.z * Zk[18 + ii] + m0.w * Zk[27 + ii]
                              + m1.x * Zk[36 + ii] + m1.y * Zk[45 + ii]
                              + m1.z * Zk[54 + ii] + m1.w * Zk[63 + ii];
                    out[(size_t)nk * NCOL + lane + (t << 6)] = val * dinv;
                }
            }
        }
        __builtin_amdgcn_wave_barrier();
    }
}

// ======== mid-tier (proven round-5) prologue: gate table + tpw transpose + node MLP =========
__global__ void __launch_bounds__(256) prologue_kernel(
        const int* __restrict__ A, const float* __restrict__ emb_table,
        const float* __restrict__ aw1, const float* __restrict__ ab1,
        const float* __restrict__ aw2, const float* __restrict__ ab2,
        const float* __restrict__ fw1, const float* __restrict__ fb1,
        const float* __restrict__ fw2, const float* __restrict__ fb2,
        const float* __restrict__ fw3, const float* __restrict__ fb3,
        const float* __restrict__ tpw,
        float* __restrict__ Ai, float4* __restrict__ tab,
        float* __restrict__ tpwT, int N) {
    __shared__ float s_w1[16 * 64];
    __shared__ float s_w2[64 * MUL];
    __shared__ float s_b1[64];
    __shared__ float s_b2[MUL];
    __shared__ float s_emb[10 * 16];

    int b = blockIdx.x;
    if (b < 32) {
        int i = b * 256 + threadIdx.x;
        if (i >= TSIZE) return;
        float len = (float)i * (TMAXLEN / TSIZE);
        float r = len * (17.0f / 5.0f);
        float h[64];
        #pragma unroll
        for (int j = 0; j < 64; j++) h[j] = fb1[j];
        #pragma unroll 1
        for (int k = 0; k < 16; k++) {
            float dk = r - (float)(k + 1);
            float ek = __expf(-dk * dk) * (4.0f / 1.12f);
            #pragma unroll
            for (int j = 0; j < 64; j++) h[j] += ek * fw1[k * 64 + j];
        }
        #pragma unroll
        for (int j = 0; j < 64; j++) h[j] = silu_f(h[j]);
        float g0 = fb3[0], g1 = fb3[3], g2 = fb3[9];
        #pragma unroll 1
        for (int j = 0; j < 64; j++) {
            float a = fb2[j];
            #pragma unroll
            for (int k = 0; k < 64; k++) a += h[k] * fw2[k * 64 + j];
            a = silu_f(a);
            g0 += a * fw3[j * 15 + 0];
            g1 += a * fw3[j * 15 + 3];
            g2 += a * fw3[j * 15 + 9];
        }
        tab[i] = make_float4(g0 * 0.125f, g1 * 0.125f, g2 * 0.125f, 0.f);
    } else if (b == 32) {
        const int pl[3] = {0, 3, 9};
        for (int i = threadIdx.x; i < 3072; i += 256) {
            int l = i >> 10, r = i & 1023;
            int u = r >> 7, v = (r >> 4) & 7, w = r & 15;
            tpwT[(l << 10) + (u << 7) + (w << 3) + v] = tpw[pl[l] * 1024 + r];
        }
    } else {
        for (int i = threadIdx.x; i < 16 * 64; i += 256) s_w1[i] = aw1[i];
        for (int i = threadIdx.x; i < 64 * MUL; i += 256) s_w2[i] = aw2[i];
        for (int i = threadIdx.x; i < 64; i += 256) s_b1[i] = ab1[i];
        for (int i = threadIdx.x; i < MUL; i += 256) s_b2[i] = ab2[i];
        for (int i = threadIdx.x; i < 160; i += 256) s_emb[i] = emb_table[i];
        __syncthreads();

        int n = (b - 33) * 256 + threadIdx.x;
        if (n >= N) return;
        int a = A[n];

        float h[64];
        #pragma unroll
        for (int j = 0; j < 64; j++) h[j] = s_b1[j];
        #pragma unroll 1
        for (int k = 0; k < 16; k++) {
            float ek = s_emb[a * 16 + k];
            #pragma unroll
            for (int j = 0; j < 64; j++) h[j] += ek * s_w1[k * 64 + j];
        }
        #pragma unroll
        for (int j = 0; j < 64; j++) h[j] = silu_f(h[j]);

        #pragma unroll 1
        for (int u = 0; u < MUL; u++) {
            float acc = s_b2[u];
            #pragma unroll
            for (int k = 0; k < 64; k++) acc += h[k] * s_w2[k * MUL + u];
            Ai[n * MUL + u] = acc;
        }
    }
}

// ---- mid-tier conv (proven round-5): 4 nodes/wave, Ai-based ----
__global__ void __launch_bounds__(256) conv_node4_kernel(
        const float* __restrict__ pos, const int* __restrict__ batch,
        const int* __restrict__ esrc,
        const float* __restrict__ shifts, const float* __restrict__ cell,
        const float* __restrict__ tpwT, const float4* __restrict__ gtab,
        const float* __restrict__ Ai, const int* __restrict__ off,
        const int* __restrict__ list,
        float* __restrict__ out, int N) {
    __shared__ float s_stage[4][17 * STG];
    __shared__ float s_Z[4][288];
    __shared__ float s_M[4][388];
    __shared__ float s_Ad[4][32];

    const int tid = threadIdx.x, wv = tid >> 6, lane = tid & 63;
    const int k = lane >> 4, s = lane & 15;
    const int base = blockIdx.x * 16 + wv * 4;
    const int n = base + k;
    const bool nv = (n < N);

    int b0 = nv ? off[n] : 0;
    int b1 = nv ? off[n + 1] : 0;
    int deg = b1 - b0;

    if (s < 8) s_Ad[wv][k * 8 + s] = nv ? Ai[(size_t)n * MUL + s] : 0.f;

    float px = 0.f, py = 0.f, pz = 0.f;
    if (nv && deg > 0) { px = pos[n * 3 + 0]; py = pos[n * 3 + 1]; pz = pos[n * 3 + 2]; }

    int md = deg;
    md = max(md, __shfl_xor(md, 16));
    md = max(md, __shfl_xor(md, 32));
    int nrnd = (md + 15) >> 4;

    float* st = s_stage[wv];

    float z[5];
    const float4* ruP[5];
    const float4* riP[5];
    #pragma unroll
    for (int j = 0; j < 5; j++) {
        int p = s + 16 * j;
        int u = (p < 72) ? (p / 9) : 0;
        int i = (p < 72) ? (p - 9 * u) : 0;
        ruP[j] = (const float4*)(st + u * STG + k * 16);
        riP[j] = (const float4*)(st + (8 + i) * STG + k * 16);
        z[j] = 0.f;
    }

    #pragma unroll 1
    for (int rnd = 0; rnd < nrnd; rnd++) {
        int sl = (rnd << 4) + s;
        float As[8], gy[9];
        #pragma unroll
        for (int u = 0; u < 8; u++) As[u] = 0.f;
        #pragma unroll
        for (int i = 0; i < 9; i++) gy[i] = 0.f;
        if (sl < deg) {
            int e = list[b0 + sl];
            float sh0 = shifts[e * 3 + 0], sh1 = shifts[e * 3 + 1], sh2 = shifts[e * 3 + 2];
            int src = esrc[e];
            float sv0 = 0.f, sv1 = 0.f, sv2 = 0.f;
            if (sh0 != 0.f || sh1 != 0.f || sh2 != 0.f) {
                int g = batch[src];
                const float* cg = cell + g * 9;
                sv0 = sh0 * cg[0] + sh1 * cg[3] + sh2 * cg[6];
                sv1 = sh0 * cg[1] + sh1 * cg[4] + sh2 * cg[7];
                sv2 = sh0 * cg[2] + sh1 * cg[5] + sh2 * cg[8];
            }
            float vx = px - pos[src * 3 + 0] + sv0;
            float vy = py - pos[src * 3 + 1] + sv1;
            float vz = pz - pos[src * 3 + 2] + sv2;
            float len = sqrtf(vx * vx + vy * vy + vz * vz);
            float inv = 1.0f / fmaxf(len, 1e-8f);
            float nx = vx * inv, ny = vy * inv, nz = vz * inv;

            float tp = fminf(len * ((float)TSIZE / TMAXLEN), (float)(TSIZE - 1));
            int ti = (int)tp; if (ti > TSIZE - 2) ti = TSIZE - 2;
            float fr = tp - (float)ti;
            float4 ga = gtab[ti], gb = gtab[ti + 1];
            float g0 = ga.x + fr * (gb.x - ga.x);
            float g1 = ga.y + fr * (gb.y - ga.y);
            float g2 = ga.z + fr * (gb.z - ga.z);

            const float s3c = 1.7320508075688772f;
            const float s15 = 3.872983346207417f;
            const float s5h = 1.118033988749895f;
            gy[0] = g0;
            gy[1] = g1 * (s3c * nx); gy[2] = g1 * (s3c * ny); gy[3] = g1 * (s3c * nz);
            gy[4] = g2 * (s15 * nx * ny); gy[5] = g2 * (s15 * ny * nz);
            gy[6] = g2 * (s5h * (3.f * nz * nz - 1.f));
            gy[7] = g2 * (s15 * nx * nz); gy[8] = g2 * (0.5f * s15 * (nx * nx - ny * ny));

            const float4* Ap = (const float4*)(Ai + (size_t)src * MUL);
            float4 A0 = Ap[0], A1 = Ap[1];
            As[0] = A0.x; As[1] = A0.y; As[2] = A0.z; As[3] = A0.w;
            As[4] = A1.x; As[5] = A1.y; As[6] = A1.z; As[7] = A1.w;
        }
        #pragma unroll
        for (int u = 0; u < 8; u++) st[u * STG + lane] = As[u];
        #pragma unroll
        for (int i = 0; i < 9; i++) st[(8 + i) * STG + lane] = gy[i];
        __builtin_amdgcn_wave_barrier();
        #pragma unroll
        for (int j = 0; j < 5; j++) {
            if (j < 4 || s < 8) {
                #pragma unroll
                for (int c = 0; c < 4; c++) {
                    float4 a = ruP[j][c], b = riP[j][c];
                    z[j] += a.x * b.x + a.y * b.y + a.z * b.z + a.w * b.w;
                }
            }
        }
        __builtin_amdgcn_wave_barrier();
    }

    #pragma unroll
    for (int j = 0; j < 5; j++)
        if (j < 4 || s < 8) s_Z[wv][k * 72 + s + 16 * j] = z[j];
    __builtin_amdgcn_wave_barrier();

    const float4* twp[6];
    int moff[6];
    #pragma unroll
    for (int t = 0; t < 6; t++) {
        int m = lane + (t << 6);
        int l = m >> 7, r = m & 127, u = r >> 4, w = r & 15;
        twp[t] = (const float4*)(tpwT + (l << 10) + (u << 7) + (w << 3));
        moff[t] = (l << 7) + (w << 3) + u;
    }
    int moffo[3], zoff[3];
    bool ov[3];
    #pragma unroll
    for (int t = 0; t < 3; t++) {
        int c = lane + (t << 6);
        ov[t] = (c < NCOL);
        int cc = ov[t] ? c : 0;
        int l, w, ii;
        if (cc < 16)      { l = 0; w = cc;            ii = 0; }
        else if (cc < 64) { l = 1; w = (cc - 16) / 3; ii = 1 + (cc - 16) % 3; }
        else              { l = 2; w = (cc - 64) / 5; ii = 4 + (cc - 64) % 5; }
        moffo[t] = (l << 7) + (w << 3);
        zoff[t] = ii;
    }

    float* M = s_M[wv];
    float* Zb = s_Z[wv];
    #pragma unroll 1
    for (int k2 = 0; k2 < 4; k2++) {
        int nk = base + k2;
        float Adk[8];
        #pragma unroll
        for (int v = 0; v < 8; v++) Adk[v] = s_Ad[wv][k2 * 8 + v];
        #pragma unroll
        for (int t = 0; t < 6; t++) {
            float4 wa = twp[t][0], wb = twp[t][1];
            M[moff[t]] = Adk[0] * wa.x + Adk[1] * wa.y + Adk[2] * wa.z + Adk[3] * wa.w
                       + Adk[4] * wb.x + Adk[5] * wb.y + Adk[6] * wb.z + Adk[7] * wb.w;
        }
        int degk = __shfl(deg, k2 * 16);
        __builtin_amdgcn_wave_barrier();
        if (nk < N) {
            float dinv = 1.0f / fmaxf((float)degk, 1.0f);
            const float* Zk = Zb + k2 * 72;
            #pragma unroll
            for (int t = 0; t < 3; t++) {
                if (ov[t]) {
                    const float4* mm = (const float4*)(M + moffo[t]);
                    float4 m0 = mm[0], m1 = mm[1];
                    int ii = zoff[t];
                    float val = m0.x * Zk[0 + ii]  + m0.y * Zk[9 + ii]
                              + m0.z * Zk[18 + ii] + m0.w * Zk[27 + ii]
                              + m1.x * Zk[36 + ii] + m1.y * Zk[45 + ii]
                              + m1.z * Zk[54 + ii] + m1.w * Zk[63 + ii];
                    out[(size_t)nk * NCOL + lane + (t << 6)] = val * dinv;
                }
            }
        }
        __builtin_amdgcn_wave_barrier();
    }
}

// ================= fallback (small ws): atomic path =================
__global__ void __launch_bounds__(256) edge_atomic_kernel(
        const float* __restrict__ pos, const int* __restrict__ batch,
        const int* __restrict__ esrc, const int* __restrict__ edst,
        const float* __restrict__ shifts, const float* __restrict__ cell,
        const float* __restrict__ fw1, const float* __restrict__ fb1,
        const float* __restrict__ fw2, const float* __restrict__ fb2,
        const float* __restrict__ fw3, const float* __restrict__ fb3,
        const float* __restrict__ tpw,
        const float* __restrict__ Ai,
        float* __restrict__ out, float* __restrict__ deg, int E) {
    __shared__ float s_w1[16 * 64];
    __shared__ float s_w2[64 * 64];
    __shared__ float s_w3[64 * 3];
    __shared__ float s_b1[64];
    __shared__ float s_b2[64];
    __shared__ float s_b3[3];
    __shared__ float s_tpw[3 * 1024];
    for (int i = threadIdx.x; i < 1024; i += blockDim.x) s_w1[i] = fw1[i];
    for (int i = threadIdx.x; i < 4096; i += blockDim.x) s_w2[i] = fw2[i];
    for (int i = threadIdx.x; i < 64; i += blockDim.x) { s_b1[i] = fb1[i]; s_b2[i] = fb2[i]; }
    for (int i = threadIdx.x; i < 192; i += blockDim.x) {
        int j = i / 3, c = i - 3 * j;
        int cc = (c == 0) ? 0 : ((c == 1) ? 3 : 9);
        s_w3[i] = fw3[j * 15 + cc];
    }
    if (threadIdx.x < 3) {
        int cc = (threadIdx.x == 0) ? 0 : ((threadIdx.x == 1) ? 3 : 9);
        s_b3[threadIdx.x] = fb3[cc];
    }
    for (int i = threadIdx.x; i < 3 * 1024; i += blockDim.x) {
        int l = i >> 10, r = i & 1023;
        int p = (l == 0) ? 0 : ((l == 1) ? 3 : 9);
        s_tpw[i] = tpw[p * 1024 + r];
    }
    __syncthreads();
    int e = blockIdx.x * blockDim.x + threadIdx.x;
    if (e >= E) return;
    int s = esrc[e], d = edst[e];
    int g = batch[s];
    float sh0 = shifts[e * 3 + 0], sh1 = shifts[e * 3 + 1], sh2 = shifts[e * 3 + 2];
    const float* cg = cell + g * 9;
    float sv0 = sh0 * cg[0] + sh1 * cg[3] + sh2 * cg[6];
    float sv1 = sh0 * cg[1] + sh1 * cg[4] + sh2 * cg[7];
    float sv2 = sh0 * cg[2] + sh1 * cg[5] + sh2 * cg[8];
    float vx = pos[d * 3 + 0] - pos[s * 3 + 0] + sv0;
    float vy = pos[d * 3 + 1] - pos[s * 3 + 1] + sv1;
    float vz = pos[d * 3 + 2] - pos[s * 3 + 2] + sv2;
    float len = sqrtf(vx * vx + vy * vy + vz * vz);
    float inv = 1.0f / fmaxf(len, 1e-8f);
    float nx = vx * inv, ny = vy * inv, nz = vz * inv;
    float r = len * (17.0f / 5.0f);
    float h[64];
    #pragma unroll
    for (int j = 0; j < 64; j++) h[j] = s_b1[j];
    #pragma unroll 1
    for (int k = 0; k < 16; k++) {
        float dk = r - (float)(k + 1);
        float ek = __expf(-dk * dk) * (4.0f / 1.12f);
        #pragma unroll
        for (int j = 0; j < 64; j++) h[j] += ek * s_w1[k * 64 + j];
    }
    #pragma unroll
    for (int j = 0; j < 64; j++) h[j] = silu_f(h[j]);
    float g0 = s_b3[0], g1 = s_b3[1], g2 = s_b3[2];
    #pragma unroll 2
    for (int j = 0; j < 64; j++) {
        float a = s_b2[j];
        #pragma unroll
        for (int k = 0; k < 64; k++) a += h[k] * s_w2[k * 64 + j];
        a = silu_f(a);
        g0 += a * s_w3[j * 3 + 0];
        g1 += a * s_w3[j * 3 + 1];
        g2 += a * s_w3[j * 3 + 2];
    }
    g0 *= 0.125f; g1 *= 0.125f; g2 *= 0.125f;
    float t0[16], t1[16], t2[16];
    #pragma unroll
    for (int w = 0; w < 16; w++) { t0[w] = 0.f; t1[w] = 0.f; t2[w] = 0.f; }
    int s8 = s * MUL, d8 = d * MUL;
    float Ad[8];
    #pragma unroll
    for (int v = 0; v < 8; v++) Ad[v] = Ai[d8 + v];
    #pragma unroll 1
    for (int u = 0; u < 8; u++) {
        float asu = Ai[s8 + u];
        int offp = u * 128;
        #pragma unroll
        for (int v = 0; v < 8; v++) {
            float p = asu * Ad[v];
            int o2 = offp + v * 16;
            #pragma unroll
            for (int w = 0; w < 16; w++) {
                t0[w] += p * s_tpw[o2 + w];
                t1[w] += p * s_tpw[1024 + o2 + w];
                t2[w] += p * s_tpw[2048 + o2 + w];
            }
        }
    }
    #pragma unroll
    for (int w = 0; w < 16; w++) { t0[w] *= g0; t1[w] *= g1; t2[w] *= g2; }
    const float s3 = 1.7320508075688772f;
    const float s15 = 3.872983346207417f;
    const float s5h = 1.118033988749895f;
    float y1_[3] = { s3 * nx, s3 * ny, s3 * nz };
    float y2_[5] = { s15 * nx * ny, s15 * ny * nz, s5h * (3.f * nz * nz - 1.f),
                     s15 * nx * nz, 0.5f * s15 * (nx * nx - ny * ny) };
    float* o = out + (size_t)d * NCOL;
    #pragma unroll
    for (int w = 0; w < 16; w++) atomicAdd(o + w, t0[w]);
    #pragma unroll
    for (int w = 0; w < 16; w++)
        #pragma unroll
        for (int i = 0; i < 3; i++) atomicAdd(o + 16 + w * 3 + i, t1[w] * y1_[i]);
    #pragma unroll
    for (int w = 0; w < 16; w++)
        #pragma unroll
        for (int i = 0; i < 5; i++) atomicAdd(o + 64 + w * 5 + i, t2[w] * y2_[i]);
    atomicAdd(deg + d, 1.0f);
}

__global__ void finalize_kernel(float* __restrict__ out, const float* __restrict__ deg, int total) {
    int idx = blockIdx.x * blockDim.x + threadIdx.x;
    if (idx >= total) return;
    int n = idx / NCOL;
    out[idx] = out[idx] / fmaxf(deg[n], 1.0f);
}

extern "C" void kernel_launch(void* const* d_in, const int* in_sizes, int n_in,
                              void* d_out, int out_size, void* d_ws, size_t ws_size,
                              hipStream_t stream) {
    const float* pos    = (const float*)d_in[0];
    const int*   A      = (const int*)d_in[1];
    const int*   batch  = (const int*)d_in[2];
    const int*   esrc   = (const int*)d_in[3];
    const int*   edst   = (const int*)d_in[4];
    const float* shifts = (const float*)d_in[5];
    const float* cellp  = (const float*)d_in[6];
    const float* embt   = (const float*)d_in[7];
    const float* aw1    = (const float*)d_in[8];
    const float* ab1    = (const float*)d_in[9];
    const float* aw2    = (const float*)d_in[10];
    const float* ab2    = (const float*)d_in[11];
    const float* fw1    = (const float*)d_in[12];
    const float* fb1    = (const float*)d_in[13];
    const float* fw2    = (const float*)d_in[14];
    const float* fb2    = (const float*)d_in[15];
    const float* fw3    = (const float*)d_in[16];
    const float* fb3    = (const float*)d_in[17];
    const float* tpw    = (const float*)d_in[18];

    int N = in_sizes[1];
    int E = in_sizes[3];
    float* out = (float*)d_out;

    int nblk = (N + 255) / 256;
    int eblk = (E + 255) / 256;

    // NEW tier: count[N] | flag[1] | off[N+1] | rank[E] | list[E] | gtab | tpwT | At[80] | bsum | bpre
    size_t need_new = ((size_t)N + 1 + (size_t)(N + 1) + (size_t)E * 2) * 4
                    + (size_t)TSIZE * 16 + 3072 * 4 + 320 + 8192 + 768;
    // mid tier (round-5 proven): Ai | count | cursor | off | list | gtab | tpwT | bsum | bpre
    size_t need_mid = (size_t)N * 32 + (size_t)N * 8 + (size_t)(N + 1) * 4
                    + (size_t)E * 4 + (size_t)TSIZE * 16 + 3072 * 4 + 8192 + 1024;

    // list packing (src | A<<27) requires N to fit in 27 bits
    bool can_pack = ((size_t)N < (size_t)(1 << 27));

    if (ws_size >= need_new && nblk <= 1024 && can_pack) {
        int*    count = (int*)d_ws;
        int*    flag  = count + N;
        int*    off   = flag + 1;
        int*    rank  = off + (N + 1);
        int*    list  = rank + E;
        float4* gtab  = (float4*)(((uintptr_t)(list + E) + 255) & ~(uintptr_t)255);
        float*  tpwT  = (float*)(gtab + TSIZE);
        float*  At    = tpwT + 3072;
        int*    bsum  = (int*)(At + 80);
        int*    bpre  = bsum + 1024;

        hipMemsetAsync(count, 0, ((size_t)N + 1) * sizeof(int), stream);  // count + flag

        front_kernel<<<GBLK + 1 + eblk, 256, 0, stream>>>(
            edst, shifts, embt, aw1, ab1, aw2, ab2,
            fw1, fb1, fw2, fb2, fw3, fb3, tpw,
            count, rank, flag, At, gtab, tpwT, E);

        scan_part_kernel<<<nblk, 256, 0, stream>>>(count, bsum, N);
        scan_top_kernel<<<1, 1024, 0, stream>>>(bsum, bpre, off, N, nblk);
        scan_write_kernel<<<nblk, 256, 0, stream>>>(count, bpre, off, N);

        permute_kernel<<<eblk, 256, 0, stream>>>(edst, esrc, A, rank, off, flag, list, E);

        conv_at_kernel<<<(N + 15) / 16, 256, 0, stream>>>(
            pos, batch, esrc, shifts, cellp, A, At, tpwT, gtab, flag, off, list, out, N);
    } else if (ws_size >= need_mid) {
        float*  Ai     = (float*)d_ws;
        int*    count  = (int*)(Ai + (size_t)N * MUL);
        int*    cursor = count + N;
        int*    off    = cursor + N;
        int*    list   = off + (N + 1);
        float4* gtab   = (float4*)(((uintptr_t)(list + E) + 255) & ~(uintptr_t)255);
        float*  tpwT   = (float*)(gtab + TSIZE);
        int*    bsum   = (int*)(tpwT + 3072);
        int*    bpre   = bsum + 1024;

        hipMemsetAsync(count, 0, (size_t)N * 2 * sizeof(int), stream);  // count + cursor

        prologue_kernel<<<33 + nblk, 256, 0, stream>>>(
            A, embt, aw1, ab1, aw2, ab2, fw1, fb1, fw2, fb2, fw3, fb3,
            tpw, Ai, gtab, tpwT, N);
        count_kernel<<<eblk, 256, 0, stream>>>(edst, count, E);

        if (nblk <= 1024) {
            scan_part_kernel<<<nblk, 256, 0, stream>>>(count, bsum, N);
            scan_top_kernel<<<1, 1024, 0, stream>>>(bsum, bpre, off, N, nblk);
            scan_write_kernel<<<nblk, 256, 0, stream>>>(count, bpre, off, N);
        } else {
            scan_kernel<<<1, 1024, 0, stream>>>(count, off, N);
        }

        fill_kernel<<<eblk, 256, 0, stream>>>(edst, off, cursor, list, E);

        conv_node4_kernel<<<(N + 15) / 16, 256, 0, stream>>>(
            pos, batch, esrc, shifts, cellp, tpwT, gtab, Ai, off, list, out, N);
    } else {
        float* Ai  = (float*)d_ws;
        float* deg = Ai + (size_t)N * MUL;
        hipMemsetAsync(out, 0, (size_t)out_size * sizeof(float), stream);
        hipMemsetAsync(deg, 0, (size_t)N * sizeof(float), stream);
        node_mlp_kernel<<<(N + 255) / 256, 256, 0, stream>>>(A, embt, aw1, ab1, aw2, ab2, Ai, N);
        edge_atomic_kernel<<<eblk, 256, 0, stream>>>(
            pos, batch, esrc, edst, shifts, cellp,
            fw1, fb1, fw2, fb2, fw3, fb3, tpw, Ai, out, deg, E);
        int total = N * NCOL;
        finalize_kernel<<<(total + 255) / 256, 256, 0, stream>>>(out, deg, total);
    }
}

// Round 10
// 197.957 us; speedup vs baseline: 1.2906x; 1.0091x over previous
//
#include <hip/hip_runtime.h>
#include <hip/hip_bf16.h>
#include <math.h>

#define MUL 8
#define NCOL 144   // 16*(1+3+5)
#define TSIZE 8192
#define TMAXLEN 8.0f
#define STG 68     // stage row stride (floats): 64 data + 4 pad, breaks 256B bank aliasing
#define GBLK 512   // gate-table blocks in front_kernel
#define SRCMASK ((1 << 27) - 1)   // list packing: src | (atomtype << 27) when no shifts

__device__ __forceinline__ float silu_f(float x) { return x / (1.0f + __expf(-x)); }

// ---------------- node MLP -> Ai[N][8] (standalone: used by fallback tier) ----------------
__global__ void node_mlp_kernel(const int* __restrict__ A,
                                const float* __restrict__ emb_table,
                                const float* __restrict__ w1,
                                const float* __restrict__ b1,
                                const float* __restrict__ w2,
                                const float* __restrict__ b2,
                                float* __restrict__ Ai, int N) {
    __shared__ float s_w1[16 * 64];
    __shared__ float s_w2[64 * MUL];
    __shared__ float s_b1[64];
    __shared__ float s_b2[MUL];
    __shared__ float s_emb[10 * 16];
    for (int i = threadIdx.x; i < 16 * 64; i += blockDim.x) s_w1[i] = w1[i];
    for (int i = threadIdx.x; i < 64 * MUL; i += blockDim.x) s_w2[i] = w2[i];
    for (int i = threadIdx.x; i < 64; i += blockDim.x) s_b1[i] = b1[i];
    for (int i = threadIdx.x; i < MUL; i += blockDim.x) s_b2[i] = b2[i];
    for (int i = threadIdx.x; i < 160; i += blockDim.x) s_emb[i] = emb_table[i];
    __syncthreads();

    int n = blockIdx.x * blockDim.x + threadIdx.x;
    if (n >= N) return;
    int a = A[n];

    float h[64];
    #pragma unroll
    for (int j = 0; j < 64; j++) h[j] = s_b1[j];
    #pragma unroll 1
    for (int k = 0; k < 16; k++) {
        float ek = s_emb[a * 16 + k];
        #pragma unroll
        for (int j = 0; j < 64; j++) h[j] += ek * s_w1[k * 64 + j];
    }
    #pragma unroll
    for (int j = 0; j < 64; j++) h[j] = silu_f(h[j]);

    #pragma unroll 1
    for (int u = 0; u < MUL; u++) {
        float acc = s_b2[u];
        #pragma unroll
        for (int k = 0; k < 64; k++) acc += h[k] * s_w2[k * MUL + u];
        Ai[n * MUL + u] = acc;
    }
}

// ======== tier-1 front kernel: wave-cooperative gate table + transpose/At + edge pass ========
__global__ void __launch_bounds__(256) front_kernel(
        const int* __restrict__ edst, const float* __restrict__ shifts,
        const float* __restrict__ emb_table,
        const float* __restrict__ aw1, const float* __restrict__ ab1,
        const float* __restrict__ aw2, const float* __restrict__ ab2,
        const float* __restrict__ fw1, const float* __restrict__ fb1,
        const float* __restrict__ fw2, const float* __restrict__ fb2,
        const float* __restrict__ fw3, const float* __restrict__ fb3,
        const float* __restrict__ tpw,
        int* __restrict__ count, int* __restrict__ rank, int* __restrict__ flag,
        float* __restrict__ At, float4* __restrict__ tab,
        float* __restrict__ tpwT, int E) {
    const int b = blockIdx.x;
    const int lane = threadIdx.x & 63, wv = threadIdx.x >> 6;

    if (b < GBLK) {
        // ---- gate table, wave-cooperative: lane j owns column j of the 64-wide MLP ----
        int gw = b * 4 + wv;
        #pragma unroll 1
        for (int e = gw; e < TSIZE; e += GBLK * 4) {
            float len = (float)e * (TMAXLEN / TSIZE);
            float r = len * (17.0f / 5.0f);
            float h = fb1[lane];
            #pragma unroll
            for (int k = 0; k < 16; k++) {
                float dk = r - (float)(k + 1);
                float ek = __expf(-dk * dk) * (4.0f / 1.12f);
                h += ek * fw1[k * 64 + lane];
            }
            h = silu_f(h);
            float a = fb2[lane];
            #pragma unroll
            for (int k = 0; k < 64; k++) a += __shfl(h, k) * fw2[k * 64 + lane];
            a = silu_f(a);
            float g0 = a * fw3[lane * 15 + 0];
            float g1 = a * fw3[lane * 15 + 3];
            float g2 = a * fw3[lane * 15 + 9];
            #pragma unroll
            for (int off = 32; off > 0; off >>= 1) {
                g0 += __shfl_xor(g0, off);
                g1 += __shfl_xor(g1, off);
                g2 += __shfl_xor(g2, off);
            }
            if (lane == 0)
                tab[e] = make_float4((fb3[0] + g0) * 0.125f,
                                     (fb3[3] + g1) * 0.125f,
                                     (fb3[9] + g2) * 0.125f, 0.f);
        }
    } else if (b == GBLK) {
        // ---- tpw transpose (proven layout) ----
        const int pl[3] = {0, 3, 9};
        for (int i = threadIdx.x; i < 3072; i += 256) {
            int l = i >> 10, r = i & 1023;
            int u = r >> 7, v = (r >> 4) & 7, w = r & 15;
            tpwT[(l << 10) + (u << 7) + (w << 3) + v] = tpw[pl[l] * 1024 + r];
        }
        // ---- At[10][8], wave-cooperative: one type per wave per pass ----
        #pragma unroll 1
        for (int ty = wv; ty < 10; ty += 4) {
            float h = ab1[lane];
            #pragma unroll
            for (int k = 0; k < 16; k++) h += emb_table[ty * 16 + k] * aw1[k * 64 + lane];
            h = silu_f(h);
            float p[8];
            #pragma unroll
            for (int u = 0; u < 8; u++) p[u] = h * aw2[lane * MUL + u];
            #pragma unroll
            for (int off = 32; off > 0; off >>= 1)
                #pragma unroll
                for (int u = 0; u < 8; u++) p[u] += __shfl_xor(p[u], off);
            if (lane == 0) {
                #pragma unroll
                for (int u = 0; u < 8; u++) At[ty * MUL + u] = ab2[u] + p[u];
            }
        }
    } else {
        // ---- edge pass: count + rank + anyShift flag ----
        int e = (b - GBLK - 1) * 256 + threadIdx.x;
        bool nz = false;
        if (e < E) {
            int d = edst[e];
            float sh0 = shifts[e * 3 + 0], sh1 = shifts[e * 3 + 1], sh2 = shifts[e * 3 + 2];
            nz = (sh0 != 0.f) || (sh1 != 0.f) || (sh2 != 0.f);
            rank[e] = atomicAdd(&count[d], 1);
        }
        if (__ballot(nz)) {
            if (lane == 0) atomicOr(flag, 1);
        }
    }
}

// ---------------- CSR build (mid-tier helpers, proven) ----------------
__global__ void count_kernel(const int* __restrict__ edst, int* __restrict__ count, int E) {
    int e = blockIdx.x * blockDim.x + threadIdx.x;
    if (e < E) atomicAdd(&count[edst[e]], 1);
}

// single-block scan (fallback for huge N)
__global__ void scan_kernel(const int* __restrict__ count, int* __restrict__ off, int N) {
    __shared__ int sums[1024];
    int L = N + 1;
    int chunk = (L + 1023) / 1024;
    int t = threadIdx.x;
    int lo = t * chunk;
    int hi = lo + chunk; if (hi > L) hi = L;
    int local = 0;
    for (int i = lo; i < hi; i++) local += (i < N) ? count[i] : 0;
    sums[t] = local;
    __syncthreads();
    for (int s = 1; s < 1024; s <<= 1) {
        int v = (t >= s) ? sums[t - s] : 0;
        __syncthreads();
        sums[t] += v;
        __syncthreads();
    }
    int run = (t == 0) ? 0 : sums[t - 1];
    for (int i = lo; i < hi; i++) {
        off[i] = run;
        run += (i < N) ? count[i] : 0;
    }
}

// hierarchical scan, phase 1: per-block sums (256 counters per block)
__global__ void __launch_bounds__(256) scan_part_kernel(
        const int* __restrict__ count, int* __restrict__ bsum, int N) {
    __shared__ int red[256];
    int t = threadIdx.x;
    int idx = blockIdx.x * 256 + t;
    red[t] = (idx < N) ? count[idx] : 0;
    __syncthreads();
    #pragma unroll
    for (int s = 128; s > 0; s >>= 1) {
        if (t < s) red[t] += red[t + s];
        __syncthreads();
    }
    if (t == 0) bsum[blockIdx.x] = red[0];
}

// hierarchical scan, phase 2 (legacy, mid-tier): exclusive scan of <=1024 block sums
__global__ void __launch_bounds__(1024) scan_top_kernel(
        const int* __restrict__ bsum, int* __restrict__ bpre,
        int* __restrict__ off, int N, int nblk) {
    __shared__ int s[1024];
    int t = threadIdx.x;
    int v = (t < nblk) ? bsum[t] : 0;
    s[t] = v;
    __syncthreads();
    for (int d = 1; d < 1024; d <<= 1) {
        int x = (t >= d) ? s[t - d] : 0;
        __syncthreads();
        s[t] += x;
        __syncthreads();
    }
    if (t < nblk) bpre[t] = s[t] - v;       // exclusive prefix of block sums
    if (t == 1023) off[N] = s[1023];        // total = E
}

// hierarchical scan, phase 3 (legacy, mid-tier): block-local exclusive scan + block offset
__global__ void __launch_bounds__(256) scan_write_kernel(
        const int* __restrict__ count, const int* __restrict__ bpre,
        int* __restrict__ off, int N) {
    __shared__ int s[256];
    int t = threadIdx.x;
    int idx = blockIdx.x * 256 + t;
    int c = (idx < N) ? count[idx] : 0;
    s[t] = c;
    __syncthreads();
    for (int d = 1; d < 256; d <<= 1) {
        int x = (t >= d) ? s[t - d] : 0;
        __syncthreads();
        s[t] += x;
        __syncthreads();
    }
    if (idx < N) off[idx] = bpre[blockIdx.x] + s[t] - c;
}

// NEW tier-1: fused scan phases 2+3 — each block computes its own prefix over bsum
// (<=1024 L2-cached ints) then the block-local exclusive scan. Removes scan_top dispatch.
__global__ void __launch_bounds__(256) scan_write2_kernel(
        const int* __restrict__ count, const int* __restrict__ bsum,
        int* __restrict__ off, int N, int nblk) {
    __shared__ int red[256];
    __shared__ int s[256];
    int t = threadIdx.x, b = blockIdx.x;
    // prefix of block sums: sum bsum[0..b-1]
    int pre = 0;
    for (int i = t; i < b; i += 256) pre += bsum[i];
    red[t] = pre;
    __syncthreads();
    #pragma unroll
    for (int st2 = 128; st2 > 0; st2 >>= 1) {
        if (t < st2) red[t] += red[t + st2];
        __syncthreads();
    }
    int bpre = red[0];   // valid: written before last __syncthreads in loop
    int idx = b * 256 + t;
    int c = (idx < N) ? count[idx] : 0;
    s[t] = c;
    __syncthreads();
    for (int d = 1; d < 256; d <<= 1) {
        int x = (t >= d) ? s[t - d] : 0;
        __syncthreads();
        s[t] += x;
        __syncthreads();
    }
    if (idx < N) off[idx] = bpre + s[t] - c;
    if (b == nblk - 1 && t == 255) off[N] = bpre + s[255];   // total = E
}

__global__ void fill_kernel(const int* __restrict__ edst, const int* __restrict__ off,
                            int* __restrict__ cursor, int* __restrict__ list, int E) {
    int e = blockIdx.x * blockDim.x + threadIdx.x;
    if (e >= E) return;
    int d = edst[e];
    int p = atomicAdd(&cursor[d], 1);
    list[off[d] + p] = e;
}

// atomic-free CSR fill using precomputed rank. When no shifts exist, stores
// src | (A[src]<<27) so conv skips the dependent A gather entirely.
__global__ void __launch_bounds__(256) permute_kernel(
        const int* __restrict__ edst, const int* __restrict__ esrc,
        const int* __restrict__ A,
        const int* __restrict__ rank, const int* __restrict__ off,
        const int* __restrict__ flagp, int* __restrict__ list, int E) {
    int e = blockIdx.x * 256 + threadIdx.x;
    if (e >= E) return;
    int d = edst[e];
    int p = off[d] + rank[e];
    if (*flagp) {
        list[p] = e;
    } else {
        int s = esrc[e];
        list[p] = s | (A[s] << 27);
    }
}

// ======== tier-1 conv: 4 nodes/wave; LDS union (stage overlays Z/M); packed list ==========
__global__ void __launch_bounds__(256) conv_at_kernel(
        const float* __restrict__ pos, const int* __restrict__ batch,
        const int* __restrict__ esrc,
        const float* __restrict__ shifts, const float* __restrict__ cell,
        const int* __restrict__ A, const float* __restrict__ At,
        const float* __restrict__ tpwT, const float4* __restrict__ gtab,
        const int* __restrict__ flagp, const int* __restrict__ off,
        const int* __restrict__ list,
        float* __restrict__ out, int N) {
    struct __align__(16) WScr {
        union {
            float stage[17 * STG];                    // 4624 B
            struct { float Z[288]; float M[388]; } zm; // 2704 B
        };
    };
    __shared__ WScr s_scr[4];       // per-wave
    __shared__ float s_Ad[4][32];   // per-wave: 4 nodes x 8 (live whole kernel)

    const int tid = threadIdx.x, wv = tid >> 6, lane = tid & 63;
    const int k = lane >> 4, s = lane & 15;
    const int base = blockIdx.x * 16 + wv * 4;
    const int n = base + k;
    const bool nv = (n < N);

    const int FL = *flagp;   // wave-uniform

    int b0 = nv ? off[n] : 0;
    int b1 = nv ? off[n + 1] : 0;
    int deg = b1 - b0;

    if (s < 8) {
        int an = nv ? A[n] : 0;
        s_Ad[wv][k * 8 + s] = nv ? At[an * 8 + s] : 0.f;
    }

    float px = 0.f, py = 0.f, pz = 0.f;
    if (nv && deg > 0) { px = pos[n * 3 + 0]; py = pos[n * 3 + 1]; pz = pos[n * 3 + 2]; }

    int md = deg;
    md = max(md, __shfl_xor(md, 16));
    md = max(md, __shfl_xor(md, 32));
    int nrnd = (md + 15) >> 4;

    float* st = s_scr[wv].stage;

    float z[5];
    const float4* ruP[5];
    const float4* riP[5];
    #pragma unroll
    for (int j = 0; j < 5; j++) {
        int p = s + 16 * j;
        int u = (p < 72) ? (p / 9) : 0;
        int i = (p < 72) ? (p - 9 * u) : 0;
        ruP[j] = (const float4*)(st + u * STG + k * 16);
        riP[j] = (const float4*)(st + (8 + i) * STG + k * 16);
        z[j] = 0.f;
    }

    #pragma unroll 1
    for (int rnd = 0; rnd < nrnd; rnd++) {
        int sl = (rnd << 4) + s;
        float As[8], gy[9];
        #pragma unroll
        for (int u = 0; u < 8; u++) As[u] = 0.f;
        #pragma unroll
        for (int i = 0; i < 9; i++) gy[i] = 0.f;
        if (sl < deg) {
            int v = list[b0 + sl];
            int src, a;
            float sv0 = 0.f, sv1 = 0.f, sv2 = 0.f;
            if (FL) {
                int e = v;
                src = esrc[e];
                a = A[src];
                float sh0 = shifts[e * 3 + 0], sh1 = shifts[e * 3 + 1], sh2 = shifts[e * 3 + 2];
                if (sh0 != 0.f || sh1 != 0.f || sh2 != 0.f) {
                    int g = batch[src];
                    const float* cg = cell + g * 9;
                    sv0 = sh0 * cg[0] + sh1 * cg[3] + sh2 * cg[6];
                    sv1 = sh0 * cg[1] + sh1 * cg[4] + sh2 * cg[7];
                    sv2 = sh0 * cg[2] + sh1 * cg[5] + sh2 * cg[8];
                }
            } else {
                src = v & SRCMASK;   // permute packed src | (A[src]<<27)
                a = v >> 27;
            }
            float vx = px - pos[src * 3 + 0] + sv0;   // dst = n
            float vy = py - pos[src * 3 + 1] + sv1;
            float vz = pz - pos[src * 3 + 2] + sv2;
            float len = sqrtf(vx * vx + vy * vy + vz * vz);
            float inv = 1.0f / fmaxf(len, 1e-8f);
            float nx = vx * inv, ny = vy * inv, nz = vz * inv;

            float tp = fminf(len * ((float)TSIZE / TMAXLEN), (float)(TSIZE - 1));
            int ti = (int)tp; if (ti > TSIZE - 2) ti = TSIZE - 2;
            float fr = tp - (float)ti;
            float4 ga = gtab[ti], gb = gtab[ti + 1];
            float g0 = ga.x + fr * (gb.x - ga.x);
            float g1 = ga.y + fr * (gb.y - ga.y);
            float g2 = ga.z + fr * (gb.z - ga.z);

            const float s3c = 1.7320508075688772f;
            const float s15 = 3.872983346207417f;
            const float s5h = 1.118033988749895f;
            gy[0] = g0;
            gy[1] = g1 * (s3c * nx); gy[2] = g1 * (s3c * ny); gy[3] = g1 * (s3c * nz);
            gy[4] = g2 * (s15 * nx * ny); gy[5] = g2 * (s15 * ny * nz);
            gy[6] = g2 * (s5h * (3.f * nz * nz - 1.f));
            gy[7] = g2 * (s15 * nx * nz); gy[8] = g2 * (0.5f * s15 * (nx * nx - ny * ny));

            const float4* Ap = (const float4*)(At + a * 8);   // 320B table, L1-resident
            float4 A0 = Ap[0], A1 = Ap[1];
            As[0] = A0.x; As[1] = A0.y; As[2] = A0.z; As[3] = A0.w;
            As[4] = A1.x; As[5] = A1.y; As[6] = A1.z; As[7] = A1.w;
        }
        #pragma unroll
        for (int u = 0; u < 8; u++) st[u * STG + lane] = As[u];
        #pragma unroll
        for (int i = 0; i < 9; i++) st[(8 + i) * STG + lane] = gy[i];
        __builtin_amdgcn_wave_barrier();
        #pragma unroll
        for (int j = 0; j < 5; j++) {
            if (j < 4 || s < 8) {
                #pragma unroll
                for (int c = 0; c < 4; c++) {
                    float4 a = ruP[j][c], b = riP[j][c];
                    z[j] += a.x * b.x + a.y * b.y + a.z * b.z + a.w * b.w;
                }
            }
        }
        __builtin_amdgcn_wave_barrier();
    }

    // publish Z (overlays dead stage region; per-wave in-order LDS + data dep make this safe)
    float* Zb = s_scr[wv].zm.Z;
    #pragma unroll
    for (int j = 0; j < 5; j++)
        if (j < 4 || s < 8) Zb[k * 72 + s + 16 * j] = z[j];
    __builtin_amdgcn_wave_barrier();

    const float4* twp[6];
    int moff[6];
    #pragma unroll
    for (int t = 0; t < 6; t++) {
        int m = lane + (t << 6);
        int l = m >> 7, r = m & 127, u = r >> 4, w = r & 15;
        twp[t] = (const float4*)(tpwT + (l << 10) + (u << 7) + (w << 3));
        moff[t] = (l << 7) + (w << 3) + u;
    }
    int moffo[3], zoff[3];
    bool ov[3];
    #pragma unroll
    for (int t = 0; t < 3; t++) {
        int c = lane + (t << 6);
        ov[t] = (c < NCOL);
        int cc = ov[t] ? c : 0;
        int l, w, ii;
        if (cc < 16)      { l = 0; w = cc;            ii = 0; }
        else if (cc < 64) { l = 1; w = (cc - 16) / 3; ii = 1 + (cc - 16) % 3; }
        else              { l = 2; w = (cc - 64) / 5; ii = 4 + (cc - 64) % 5; }
        moffo[t] = (l << 7) + (w << 3);
        zoff[t] = ii;
    }

    float* M = s_scr[wv].zm.M;
    #pragma unroll 1
    for (int k2 = 0; k2 < 4; k2++) {
        int nk = base + k2;
        float Adk[8];
        #pragma unroll
        for (int v = 0; v < 8; v++) Adk[v] = s_Ad[wv][k2 * 8 + v];  // broadcast
        #pragma unroll
        for (int t = 0; t < 6; t++) {
            float4 wa = twp[t][0], wb = twp[t][1];
            M[moff[t]] = Adk[0] * wa.x + Adk[1] * wa.y + Adk[2] * wa.z + Adk[3] * wa.w
                       + Adk[4] * wb.x + Adk[5] * wb.y + Adk[6] * wb.z + Adk[7] * wb.w;
        }
        int degk = __shfl(deg, k2 * 16);
        __builtin_amdgcn_wave_barrier();
        if (nk < N) {
            float dinv = 1.0f / fmaxf((float)degk, 1.0f);
            const float* Zk = Zb + k2 * 72;
            #pragma unroll
            for (int t = 0; t < 3; t++) {
                if (ov[t]) {
                    const float4* mm = (const float4*)(M + moffo[t]);
                    float4 m0 = mm[0], m1 = mm[1];
                    int ii = zoff[t];
                    float val = m0.x * Zk[0 + ii]  + m0.y * Zk[9 + ii]
                              + m0.z * Zk[18 + ii] + m0.w * Zk[27 + ii]
                              + m1.x * Zk[36 + ii] + m1.y * Zk[45 + ii]
                              + m1.z * Zk[54 + ii] + m1.w * Zk[63 + ii];
                    out[(size_t)nk * NCOL + lane + (t << 6)] = val * dinv;
                }
            }
        }
        __builtin_amdgcn_wave_barrier();
    }
}

// ======== mid-tier (proven round-5) prologue: gate table + tpw transpose + node MLP =========
__global__ void __launch_bounds__(256) prologue_kernel(
        const int* __restrict__ A, const float* __restrict__ emb_table,
        const float* __restrict__ aw1, const float* __restrict__ ab1,
        const float* __restrict__ aw2, const float* __restrict__ ab2,
        const float* __restrict__ fw1, const float* __restrict__ fb1,
        const float* __restrict__ fw2, const float* __restrict__ fb2,
        const float* __restrict__ fw3, const float* __restrict__ fb3,
        const float* __restrict__ tpw,
        float* __restrict__ Ai, float4* __restrict__ tab,
        float* __restrict__ tpwT, int N) {
    __shared__ float s_w1[16 * 64];
    __shared__ float s_w2[64 * MUL];
    __shared__ float s_b1[64];
    __shared__ float s_b2[MUL];
    __shared__ float s_emb[10 * 16];

    int b = blockIdx.x;
    if (b < 32) {
        int i = b * 256 + threadIdx.x;
        if (i >= TSIZE) return;
        float len = (float)i * (TMAXLEN / TSIZE);
        float r = len * (17.0f / 5.0f);
        float h[64];
        #pragma unroll
        for (int j = 0; j < 64; j++) h[j] = fb1[j];
        #pragma unroll 1
        for (int k = 0; k < 16; k++) {
            float dk = r - (float)(k + 1);
            float ek = __expf(-dk * dk) * (4.0f / 1.12f);
            #pragma unroll
            for (int j = 0; j < 64; j++) h[j] += ek * fw1[k * 64 + j];
        }
        #pragma unroll
        for (int j = 0; j < 64; j++) h[j] = silu_f(h[j]);
        float g0 = fb3[0], g1 = fb3[3], g2 = fb3[9];
        #pragma unroll 1
        for (int j = 0; j < 64; j++) {
            float a = fb2[j];
            #pragma unroll
            for (int k = 0; k < 64; k++) a += h[k] * fw2[k * 64 + j];
            a = silu_f(a);
            g0 += a * fw3[j * 15 + 0];
            g1 += a * fw3[j * 15 + 3];
            g2 += a * fw3[j * 15 + 9];
        }
        tab[i] = make_float4(g0 * 0.125f, g1 * 0.125f, g2 * 0.125f, 0.f);
    } else if (b == 32) {
        const int pl[3] = {0, 3, 9};
        for (int i = threadIdx.x; i < 3072; i += 256) {
            int l = i >> 10, r = i & 1023;
            int u = r >> 7, v = (r >> 4) & 7, w = r & 15;
            tpwT[(l << 10) + (u << 7) + (w << 3) + v] = tpw[pl[l] * 1024 + r];
        }
    } else {
        for (int i = threadIdx.x; i < 16 * 64; i += 256) s_w1[i] = aw1[i];
        for (int i = threadIdx.x; i < 64 * MUL; i += 256) s_w2[i] = aw2[i];
        for (int i = threadIdx.x; i < 64; i += 256) s_b1[i] = ab1[i];
        for (int i = threadIdx.x; i < MUL; i += 256) s_b2[i] = ab2[i];
        for (int i = threadIdx.x; i < 160; i += 256) s_emb[i] = emb_table[i];
        __syncthreads();

        int n = (b - 33) * 256 + threadIdx.x;
        if (n >= N) return;
        int a = A[n];

        float h[64];
        #pragma unroll
        for (int j = 0; j < 64; j++) h[j] = s_b1[j];
        #pragma unroll 1
        for (int k = 0; k < 16; k++) {
            float ek = s_emb[a * 16 + k];
            #pragma unroll
            for (int j = 0; j < 64; j++) h[j] += ek * s_w1[k * 64 + j];
        }
        #pragma unroll
        for (int j = 0; j < 64; j++) h[j] = silu_f(h[j]);

        #pragma unroll 1
        for (int u = 0; u < MUL; u++) {
            float acc = s_b2[u];
            #pragma unroll
            for (int k = 0; k < 64; k++) acc += h[k] * s_w2[k * MUL + u];
            Ai[n * MUL + u] = acc;
        }
    }
}

// ---- mid-tier conv (proven round-5): 4 nodes/wave, Ai-based ----
__global__ void __launch_bounds__(256) conv_node4_kernel(
        const float* __restrict__ pos, const int* __restrict__ batch,
        const int* __restrict__ esrc,
        const float* __restrict__ shifts, const float* __restrict__ cell,
        const float* __restrict__ tpwT, const float4* __restrict__ gtab,
        const float* __restrict__ Ai, const int* __restrict__ off,
        const int* __restrict__ list,
        float* __restrict__ out, int N) {
    __shared__ float s_stage[4][17 * STG];
    __shared__ float s_Z[4][288];
    __shared__ float s_M[4][388];
    __shared__ float s_Ad[4][32];

    const int tid = threadIdx.x, wv = tid >> 6, lane = tid & 63;
    const int k = lane >> 4, s = lane & 15;
    const int base = blockIdx.x * 16 + wv * 4;
    const int n = base + k;
    const bool nv = (n < N);

    int b0 = nv ? off[n] : 0;
    int b1 = nv ? off[n + 1] : 0;
    int deg = b1 - b0;

    if (s < 8) s_Ad[wv][k * 8 + s] = nv ? Ai[(size_t)n * MUL + s] : 0.f;

    float px = 0.f, py = 0.f, pz = 0.f;
    if (nv && deg > 0) { px = pos[n * 3 + 0]; py = pos[n * 3 + 1]; pz = pos[n * 3 + 2]; }

    int md = deg;
    md = max(md, __shfl_xor(md, 16));
    md = max(md, __shfl_xor(md, 32));
    int nrnd = (md + 15) >> 4;

    float* st = s_stage[wv];

    float z[5];
    const float4* ruP[5];
    const float4* riP[5];
    #pragma unroll
    for (int j = 0; j < 5; j++) {
        int p = s + 16 * j;
        int u = (p < 72) ? (p / 9) : 0;
        int i = (p < 72) ? (p - 9 * u) : 0;
        ruP[j] = (const float4*)(st + u * STG + k * 16);
        riP[j] = (const float4*)(st + (8 + i) * STG + k * 16);
        z[j] = 0.f;
    }

    #pragma unroll 1
    for (int rnd = 0; rnd < nrnd; rnd++) {
        int sl = (rnd << 4) + s;
        float As[8], gy[9];
        #pragma unroll
        for (int u = 0; u < 8; u++) As[u] = 0.f;
        #pragma unroll
        for (int i = 0; i < 9; i++) gy[i] = 0.f;
        if (sl < deg) {
            int e = list[b0 + sl];
            float sh0 = shifts[e * 3 + 0], sh1 = shifts[e * 3 + 1], sh2 = shifts[e * 3 + 2];
            int src = esrc[e];
            float sv0 = 0.f, sv1 = 0.f, sv2 = 0.f;
            if (sh0 != 0.f || sh1 != 0.f || sh2 != 0.f) {
                int g = batch[src];
                const float* cg = cell + g * 9;
                sv0 = sh0 * cg[0] + sh1 * cg[3] + sh2 * cg[6];
                sv1 = sh0 * cg[1] + sh1 * cg[4] + sh2 * cg[7];
                sv2 = sh0 * cg[2] + sh1 * cg[5] + sh2 * cg[8];
            }
            float vx = px - pos[src * 3 + 0] + sv0;
            float vy = py - pos[src * 3 + 1] + sv1;
            float vz = pz - pos[src * 3 + 2] + sv2;
            float len = sqrtf(vx * vx + vy * vy + vz * vz);
            float inv = 1.0f / fmaxf(len, 1e-8f);
            float nx = vx * inv, ny = vy * inv, nz = vz * inv;

            float tp = fminf(len * ((float)TSIZE / TMAXLEN), (float)(TSIZE - 1));
            int ti = (int)tp; if (ti > TSIZE - 2) ti = TSIZE - 2;
            float fr = tp - (float)ti;
            float4 ga = gtab[ti], gb = gtab[ti + 1];
            float g0 = ga.x + fr * (gb.x - ga.x);
            float g1 = ga.y + fr * (gb.y - ga.y);
            float g2 = ga.z + fr * (gb.z - ga.z);

            const float s3c = 1.7320508075688772f;
            const float s15 = 3.872983346207417f;
            const float s5h = 1.118033988749895f;
            gy[0] = g0;
            gy[1] = g1 * (s3c * nx); gy[2] = g1 * (s3c * ny); gy[3] = g1 * (s3c * nz);
            gy[4] = g2 * (s15 * nx * ny); gy[5] = g2 * (s15 * ny * nz);
            gy[6] = g2 * (s5h * (3.f * nz * nz - 1.f));
            gy[7] = g2 * (s15 * nx * nz); gy[8] = g2 * (0.5f * s15 * (nx * nx - ny * ny));

            const float4* Ap = (const float4*)(Ai + (size_t)src * MUL);
            float4 A0 = Ap[0], A1 = Ap[1];
            As[0] = A0.x; As[1] = A0.y; As[2] = A0.z; As[3] = A0.w;
            As[4] = A1.x; As[5] = A1.y; As[6] = A1.z; As[7] = A1.w;
        }
        #pragma unroll
        for (int u = 0; u < 8; u++) st[u * STG + lane] = As[u];
        #pragma unroll
        for (int i = 0; i < 9; i++) st[(8 + i) * STG + lane] = gy[i];
        __builtin_amdgcn_wave_barrier();
        #pragma unroll
        for (int j = 0; j < 5; j++) {
            if (j < 4 || s < 8) {
                #pragma unroll
                for (int c = 0; c < 4; c++) {
                    float4 a = ruP[j][c], b = riP[j][c];
                    z[j] += a.x * b.x + a.y * b.y + a.z * b.z + a.w * b.w;
                }
            }
        }
        __builtin_amdgcn_wave_barrier();
    }

    #pragma unroll
    for (int j = 0; j < 5; j++)
        if (j < 4 || s < 8) s_Z[wv][k * 72 + s + 16 * j] = z[j];
    __builtin_amdgcn_wave_barrier();

    const float4* twp[6];
    int moff[6];
    #pragma unroll
    for (int t = 0; t < 6; t++) {
        int m = lane + (t << 6);
        int l = m >> 7, r = m & 127, u = r >> 4, w = r & 15;
        twp[t] = (const float4*)(tpwT + (l << 10) + (u << 7) + (w << 3));
        moff[t] = (l << 7) + (w << 3) + u;
    }
    int moffo[3], zoff[3];
    bool ov[3];
    #pragma unroll
    for (int t = 0; t < 3; t++) {
        int c = lane + (t << 6);
        ov[t] = (c < NCOL);
        int cc = ov[t] ? c : 0;
        int l, w, ii;
        if (cc < 16)      { l = 0; w = cc;            ii = 0; }
        else if (cc < 64) { l = 1; w = (cc - 16) / 3; ii = 1 + (cc - 16) % 3; }
        else              { l = 2; w = (cc - 64) / 5; ii = 4 + (cc - 64) % 5; }
        moffo[t] = (l << 7) + (w << 3);
        zoff[t] = ii;
    }

    float* M = s_M[wv];
    float* Zb = s_Z[wv];
    #pragma unroll 1
    for (int k2 = 0; k2 < 4; k2++) {
        int nk = base + k2;
        float Adk[8];
        #pragma unroll
        for (int v = 0; v < 8; v++) Adk[v] = s_Ad[wv][k2 * 8 + v];
        #pragma unroll
        for (int t = 0; t < 6; t++) {
            float4 wa = twp[t][0], wb = twp[t][1];
            M[moff[t]] = Adk[0] * wa.x + Adk[1] * wa.y + Adk[2] * wa.z + Adk[3] * wa.w
                       + Adk[4] * wb.x + Adk[5] * wb.y + Adk[6] * wb.z + Adk[7] * wb.w;
        }
        int degk = __shfl(deg, k2 * 16);
        __builtin_amdgcn_wave_barrier();
        if (nk < N) {
            float dinv = 1.0f / fmaxf((float)degk, 1.0f);
            const float* Zk = Zb + k2 * 72;
            #pragma unroll
            for (int t = 0; t < 3; t++) {
                if (ov[t]) {
                    const float4* mm = (const float4*)(M + moffo[t]);
                    float4 m0 = mm[0], m1 = mm[1];
                    int ii = zoff[t];
                    float val = m0.x * Zk[0 + ii]  + m0.y * Zk[9 + ii]
                              + m0.z * Zk[18 + ii] + m0.w * Zk[27 + ii]
                              + m1.x * Zk[36 + ii] + m1.y * Zk[45 + ii]
                              + m1.z * Zk[54 + ii] + m1.w * Zk[63 + ii];
                    out[(size_t)nk * NCOL + lane + (t << 6)] = val * dinv;
                }
            }
        }
        __builtin_amdgcn_wave_barrier();
    }
}

// ================= fallback (small ws): atomic path =================
__global__ void __launch_bounds__(256) edge_atomic_kernel(
        const float* __restrict__ pos, const int* __restrict__ batch,
        const int* __restrict__ esrc, const int* __restrict__ edst,
        const float* __restrict__ shifts, const float* __restrict__ cell,
        const float* __restrict__ fw1, const float* __restrict__ fb1,
        const float* __restrict__ fw2, const float* __restrict__ fb2,
        const float* __restrict__ fw3, const float* __restrict__ fb3,
        const float* __restrict__ tpw,
        const float* __restrict__ Ai,
        float* __restrict__ out, float* __restrict__ deg, int E) {
    __shared__ float s_w1[16 * 64];
    __shared__ float s_w2[64 * 64];
    __shared__ float s_w3[64 * 3];
    __shared__ float s_b1[64];
    __shared__ float s_b2[64];
    __shared__ float s_b3[3];
    __shared__ float s_tpw[3 * 1024];
    for (int i = threadIdx.x; i < 1024; i += blockDim.x) s_w1[i] = fw1[i];
    for (int i = threadIdx.x; i < 4096; i += blockDim.x) s_w2[i] = fw2[i];
    for (int i = threadIdx.x; i < 64; i += blockDim.x) { s_b1[i] = fb1[i]; s_b2[i] = fb2[i]; }
    for (int i = threadIdx.x; i < 192; i += blockDim.x) {
        int j = i / 3, c = i - 3 * j;
        int cc = (c == 0) ? 0 : ((c == 1) ? 3 : 9);
        s_w3[i] = fw3[j * 15 + cc];
    }
    if (threadIdx.x < 3) {
        int cc = (threadIdx.x == 0) ? 0 : ((threadIdx.x == 1) ? 3 : 9);
        s_b3[threadIdx.x] = fb3[cc];
    }
    for (int i = threadIdx.x; i < 3 * 1024; i += blockDim.x) {
        int l = i >> 10, r = i & 1023;
        int p = (l == 0) ? 0 : ((l == 1) ? 3 : 9);
        s_tpw[i] = tpw[p * 1024 + r];
    }
    __syncthreads();
    int e = blockIdx.x * blockDim.x + threadIdx.x;
    if (e >= E) return;
    int s = esrc[e], d = edst[e];
    int g = batch[s];
    float sh0 = shifts[e * 3 + 0], sh1 = shifts[e * 3 + 1], sh2 = shifts[e * 3 + 2];
    const float* cg = cell + g * 9;
    float sv0 = sh0 * cg[0] + sh1 * cg[3] + sh2 * cg[6];
    float sv1 = sh0 * cg[1] + sh1 * cg[4] + sh2 * cg[7];
    float sv2 = sh0 * cg[2] + sh1 * cg[5] + sh2 * cg[8];
    float vx = pos[d * 3 + 0] - pos[s * 3 + 0] + sv0;
    float vy = pos[d * 3 + 1] - pos[s * 3 + 1] + sv1;
    float vz = pos[d * 3 + 2] - pos[s * 3 + 2] + sv2;
    float len = sqrtf(vx * vx + vy * vy + vz * vz);
    float inv = 1.0f / fmaxf(len, 1e-8f);
    float nx = vx * inv, ny = vy * inv, nz = vz * inv;
    float r = len * (17.0f / 5.0f);
    float h[64];
    #pragma unroll
    for (int j = 0; j < 64; j++) h[j] = s_b1[j];
    #pragma unroll 1
    for (int k = 0; k < 16; k++) {
        float dk = r - (float)(k + 1);
        float ek = __expf(-dk * dk) * (4.0f / 1.12f);
        #pragma unroll
        for (int j = 0; j < 64; j++) h[j] += ek * s_w1[k * 64 + j];
    }
    #pragma unroll
    for (int j = 0; j < 64; j++) h[j] = silu_f(h[j]);
    float g0 = s_b3[0], g1 = s_b3[1], g2 = s_b3[2];
    #pragma unroll 2
    for (int j = 0; j < 64; j++) {
        float a = s_b2[j];
        #pragma unroll
        for (int k = 0; k < 64; k++) a += h[k] * s_w2[k * 64 + j];
        a = silu_f(a);
        g0 += a * s_w3[j * 3 + 0];
        g1 += a * s_w3[j * 3 + 1];
        g2 += a * s_w3[j * 3 + 2];
    }
    g0 *= 0.125f; g1 *= 0.125f; g2 *= 0.125f;
    float t0[16], t1[16], t2[16];
    #pragma unroll
    for (int w = 0; w < 16; w++) { t0[w] = 0.f; t1[w] = 0.f; t2[w] = 0.f; }
    int s8 = s * MUL, d8 = d * MUL;
    float Ad[8];
    #pragma unroll
    for (int v = 0; v < 8; v++) Ad[v] = Ai[d8 + v];
    #pragma unroll 1
    for (int u = 0; u < 8; u++) {
        float asu = Ai[s8 + u];
        int offp = u * 128;
        #pragma unroll
        for (int v = 0; v < 8; v++) {
            float p = asu * Ad[v];
            int o2 = offp + v * 16;
            #pragma unroll
            for (int w = 0; w < 16; w++) {
                t0[w] += p * s_tpw[o2 + w];
                t1[w] += p * s_tpw[1024 + o2 + w];
                t2[w] += p * s_tpw[2048 + o2 + w];
            }
        }
    }
    #pragma unroll
    for (int w = 0; w < 16; w++) { t0[w] *= g0; t1[w] *= g1; t2[w] *= g2; }
    const float s3 = 1.7320508075688772f;
    const float s15 = 3.872983346207417f;
    const float s5h = 1.118033988749895f;
    float y1_[3] = { s3 * nx, s3 * ny, s3 * nz };
    float y2_[5] = { s15 * nx * ny, s15 * ny * nz, s5h * (3.f * nz * nz - 1.f),
                     s15 * nx * nz, 0.5f * s15 * (nx * nx - ny * ny) };
    float* o = out + (size_t)d * NCOL;
    #pragma unroll
    for (int w = 0; w < 16; w++) atomicAdd(o + w, t0[w]);
    #pragma unroll
    for (int w = 0; w < 16; w++)
        #pragma unroll
        for (int i = 0; i < 3; i++) atomicAdd(o + 16 + w * 3 + i, t1[w] * y1_[i]);
    #pragma unroll
    for (int w = 0; w < 16; w++)
        #pragma unroll
        for (int i = 0; i < 5; i++) atomicAdd(o + 64 + w * 5 + i, t2[w] * y2_[i]);
    atomicAdd(deg + d, 1.0f);
}

__global__ void finalize_kernel(float* __restrict__ out, const float* __restrict__ deg, int total) {
    int idx = blockIdx.x * blockDim.x + threadIdx.x;
    if (idx >= total) return;
    int n = idx / NCOL;
    out[idx] = out[idx] / fmaxf(deg[n], 1.0f);
}

extern "C" void kernel_launch(void* const* d_in, const int* in_sizes, int n_in,
                              void* d_out, int out_size, void* d_ws, size_t ws_size,
                              hipStream_t stream) {
    const float* pos    = (const float*)d_in[0];
    const int*   A      = (const int*)d_in[1];
    const int*   batch  = (const int*)d_in[2];
    const int*   esrc   = (const int*)d_in[3];
    const int*   edst   = (const int*)d_in[4];
    const float* shifts = (const float*)d_in[5];
    const float* cellp  = (const float*)d_in[6];
    const float* embt   = (const float*)d_in[7];
    const float* aw1    = (const float*)d_in[8];
    const float* ab1    = (const float*)d_in[9];
    const float* aw2    = (const float*)d_in[10];
    const float* ab2    = (const float*)d_in[11];
    const float* fw1    = (const float*)d_in[12];
    const float* fb1    = (const float*)d_in[13];
    const float* fw2    = (const float*)d_in[14];
    const float* fb2    = (const float*)d_in[15];
    const float* fw3    = (const float*)d_in[16];
    const float* fb3    = (const float*)d_in[17];
    const float* tpw    = (const float*)d_in[18];

    int N = in_sizes[1];
    int E = in_sizes[3];
    float* out = (float*)d_out;

    int nblk = (N + 255) / 256;
    int eblk = (E + 255) / 256;

    // NEW tier: count[N] | flag[1] | off[N+1] | rank[E] | list[E] | gtab | tpwT | At[80] | bsum
    size_t need_new = ((size_t)N + 1 + (size_t)(N + 1) + (size_t)E * 2) * 4
                    + (size_t)TSIZE * 16 + 3072 * 4 + 320 + 8192 + 768;
    // mid tier (round-5 proven): Ai | count | cursor | off | list | gtab | tpwT | bsum | bpre
    size_t need_mid = (size_t)N * 32 + (size_t)N * 8 + (size_t)(N + 1) * 4
                    + (size_t)E * 4 + (size_t)TSIZE * 16 + 3072 * 4 + 8192 + 1024;

    // list packing (src | A<<27) requires N to fit in 27 bits
    bool can_pack = ((size_t)N < (size_t)(1 << 27));

    if (ws_size >= need_new && nblk <= 1024 && can_pack) {
        int*    count = (int*)d_ws;
        int*    flag  = count + N;
        int*    off   = flag + 1;
        int*    rank  = off + (N + 1);
        int*    list  = rank + E;
        float4* gtab  = (float4*)(((uintptr_t)(list + E) + 255) & ~(uintptr_t)255);
        float*  tpwT  = (float*)(gtab + TSIZE);
        float*  At    = tpwT + 3072;
        int*    bsum  = (int*)(At + 80);

        hipMemsetAsync(count, 0, ((size_t)N + 1) * sizeof(int), stream);  // count + flag

        front_kernel<<<GBLK + 1 + eblk, 256, 0, stream>>>(
            edst, shifts, embt, aw1, ab1, aw2, ab2,
            fw1, fb1, fw2, fb2, fw3, fb3, tpw,
            count, rank, flag, At, gtab, tpwT, E);

        scan_part_kernel<<<nblk, 256, 0, stream>>>(count, bsum, N);
        scan_write2_kernel<<<nblk, 256, 0, stream>>>(count, bsum, off, N, nblk);

        permute_kernel<<<eblk, 256, 0, stream>>>(edst, esrc, A, rank, off, flag, list, E);

        conv_at_kernel<<<(N + 15) / 16, 256, 0, stream>>>(
            pos, batch, esrc, shifts, cellp, A, At, tpwT, gtab, flag, off, list, out, N);
    } else if (ws_size >= need_mid) {
        float*  Ai     = (float*)d_ws;
        int*    count  = (int*)(Ai + (size_t)N * MUL);
        int*    cursor = count + N;
        int*    off    = cursor + N;
        int*    list   = off + (N + 1);
        float4* gtab   = (float4*)(((uintptr_t)(list + E) + 255) & ~(uintptr_t)255);
        float*  tpwT   = (float*)(gtab + TSIZE);
        int*    bsum   = (int*)(tpwT + 3072);
        int*    bpre   = bsum + 1024;

        hipMemsetAsync(count, 0, (size_t)N * 2 * sizeof(int), stream);  // count + cursor

        prologue_kernel<<<33 + nblk, 256, 0, stream>>>(
            A, embt, aw1, ab1, aw2, ab2, fw1, fb1, fw2, fb2, fw3, fb3,
            tpw, Ai, gtab, tpwT, N);
        count_kernel<<<eblk, 256, 0, stream>>>(edst, count, E);

        if (nblk <= 1024) {
            scan_part_kernel<<<nblk, 256, 0, stream>>>(count, bsum, N);
            scan_top_kernel<<<1, 1024, 0, stream>>>(bsum, bpre, off, N, nblk);
            scan_write_kernel<<<nblk, 256, 0, stream>>>(count, bpre, off, N);
        } else {
            scan_kernel<<<1, 1024, 0, stream>>>(count, off, N);
        }

        fill_kernel<<<eblk, 256, 0, stream>>>(edst, off, cursor, list, E);

        conv_node4_kernel<<<(N + 15) / 16, 256, 0, stream>>>(
            pos, batch, esrc, shifts, cellp, tpwT, gtab, Ai, off, list, out, N);
    } else {
        float* Ai  = (float*)d_ws;
        float* deg = Ai + (size_t)N * MUL;
        hipMemsetAsync(out, 0, (size_t)out_size * sizeof(float), stream);
        hipMemsetAsync(deg, 0, (size_t)N * sizeof(float), stream);
        node_mlp_kernel<<<(N + 255) / 256, 256, 0, stream>>>(A, embt, aw1, ab1, aw2, ab2, Ai, N);
        edge_atomic_kernel<<<eblk, 256, 0, stream>>>(
            pos, batch, esrc, edst, shifts, cellp,
            fw1, fb1, fw2, fb2, fw3, fb3, tpw, Ai, out, deg, E);
        int total = N * NCOL;
        finalize_kernel<<<(total + 255) / 256, 256, 0, stream>>>(out, deg, total);
    }
}